// Round 2
// baseline (553.763 us; speedup 1.0000x reference)
//
#include <hip/hip_runtime.h>

#define S_LEN 2048
#define DMODEL 1024
#define NH 16
#define NKVH 4
#define DKH 64
#define KVD 256
#define SCALE_LOG2E 0.18033688f  // (1/sqrt(64)) * log2(e)

typedef __bf16 bf16;
typedef bf16  bf16x8 __attribute__((ext_vector_type(8)));
typedef bf16  bf16x4 __attribute__((ext_vector_type(4)));
typedef float f32x4  __attribute__((ext_vector_type(4)));
typedef bf16x8 bf16x8_a __attribute__((may_alias));
typedef bf16x4 bf16x4_a __attribute__((may_alias));
typedef float f32x4g __attribute__((ext_vector_type(4), may_alias));

__device__ __forceinline__ void gll16(const bf16* g, bf16* l) {
    __builtin_amdgcn_global_load_lds(
        (const __attribute__((address_space(1))) void*)g,
        (__attribute__((address_space(3))) void*)l, 16, 0, 0);
}

// ---------------- fp32 -> bf16 cast (vectorized) ----------------
__global__ __launch_bounds__(256) void cast_bf16(const float* __restrict__ in,
                                                 bf16* __restrict__ out, int n4) {
    int stride = gridDim.x * blockDim.x;
    for (int i = blockIdx.x * blockDim.x + threadIdx.x; i < n4; i += stride) {
        f32x4g v = ((const f32x4g*)in)[i];
        bf16x4 o;
        o[0] = (bf16)v[0]; o[1] = (bf16)v[1]; o[2] = (bf16)v[2]; o[3] = (bf16)v[3];
        ((bf16x4*)out)[i] = o;
    }
}

// ---------------- NT GEMM: C[m][n] = sum_k A[m][k]*Bw[n][k] + bias[n] ----------------
template <int OUTF32>
__global__ __launch_bounds__(256) void gemm_bt(const bf16* __restrict__ A,
                                               const bf16* __restrict__ Bw,
                                               const float* __restrict__ bias,
                                               void* __restrict__ Cout,
                                               int M, int N, int K) {
    __shared__ bf16 As[4096];  // 128 x 32
    __shared__ bf16 Bs[4096];
    const int bm = blockIdx.x, bn = blockIdx.y;
    const int tid = threadIdx.x, wave = tid >> 6, lane = tid & 63;
    const int l15 = lane & 15, lhi = lane >> 4;
    const int wr = (wave >> 1) * 64, wc = (wave & 1) * 64;
    f32x4 acc[4][4] = {};
    const size_t arow0 = (size_t)bm * 128 * K;
    const size_t brow0 = (size_t)bn * 128 * K;

    for (int kt = 0; kt < K; kt += 32) {
#pragma unroll
        for (int i = 0; i < 2; ++i) {
            int base = i * 2048 + wave * 512;
            int flat = base + lane * 8;
            int r = flat >> 5, c = flat & 31;
            gll16(A + arow0 + (size_t)r * K + kt + c, &As[base]);
            gll16(Bw + brow0 + (size_t)r * K + kt + c, &Bs[base]);
        }
        __syncthreads();
        bf16x8 af[4], bfr[4];
#pragma unroll
        for (int mi = 0; mi < 4; ++mi)
            af[mi] = *(const bf16x8_a*)&As[(wr + mi * 16 + l15) * 32 + lhi * 8];
#pragma unroll
        for (int ni = 0; ni < 4; ++ni)
            bfr[ni] = *(const bf16x8_a*)&Bs[(wc + ni * 16 + l15) * 32 + lhi * 8];
#pragma unroll
        for (int mi = 0; mi < 4; ++mi)
#pragma unroll
            for (int ni = 0; ni < 4; ++ni)
                acc[mi][ni] = __builtin_amdgcn_mfma_f32_16x16x32_bf16(
                    af[mi], bfr[ni], acc[mi][ni], 0, 0, 0);
        __syncthreads();
    }
#pragma unroll
    for (int mi = 0; mi < 4; ++mi)
#pragma unroll
        for (int ni = 0; ni < 4; ++ni)
#pragma unroll
            for (int j = 0; j < 4; ++j) {
                int row = bm * 128 + wr + mi * 16 + lhi * 4 + j;
                int col = bn * 128 + wc + ni * 16 + l15;
                float v = acc[mi][ni][j] + bias[col];
                if (OUTF32)
                    ((float*)Cout)[(size_t)row * N + col] = v;
                else
                    ((bf16*)Cout)[(size_t)row * N + col] = (bf16)v;
            }
}

// ---------------- V transpose: Vp[b*2048+s][g*64+d] -> VT[b][g][d][s] ----------------
__global__ __launch_bounds__(256) void vtrans(const bf16* __restrict__ V,
                                              bf16* __restrict__ VT) {
    __shared__ bf16 t[64][65];
    const int s0 = blockIdx.x * 64;
    const int bg = blockIdx.y;
    const int b = bg >> 2, g = bg & 3;
#pragma unroll
    for (int i = 0; i < 16; ++i) {
        int flat = threadIdx.x + i * 256;
        int r = flat >> 6, c = flat & 63;
        t[c][r] = V[(size_t)(b * S_LEN + s0 + r) * KVD + g * DKH + c];
    }
    __syncthreads();
#pragma unroll
    for (int i = 0; i < 16; ++i) {
        int flat = threadIdx.x + i * 256;
        int d = flat >> 6, si = flat & 63;
        VT[((size_t)bg * DKH + d) * S_LEN + s0 + si] = t[d][si];
    }
}

// ---------------- denominator kernel ----------------
// grid (B*NH*(S/64), 4 key-quarters); block 256 = 4 waves x 16 q-rows.
// Swapped QK^T: per-lane partial sum (q = lane&15), no hot-loop shuffles.
__global__ __launch_bounds__(256) void attn_denom(const bf16* __restrict__ Qp,
                                                  const bf16* __restrict__ Kp,
                                                  float* __restrict__ part) {
    const int bh = blockIdx.x >> 5;
    const int qt = blockIdx.x & 31;
    const int ky = blockIdx.y;
    const int h = bh & (NH - 1), b = bh >> 4, g = h >> 2;
    const int wave = threadIdx.x >> 6, lane = threadIdx.x & 63;
    const int l15 = lane & 15, lhi = lane >> 4;
    const int qrow0 = qt * 64 + wave * 16;

    const bf16* qbase = Qp + (size_t)(b * S_LEN + qrow0 + l15) * DMODEL + h * DKH + lhi * 8;
    bf16x8 aq0 = *(const bf16x8_a*)qbase;
    bf16x8 aq1 = *(const bf16x8_a*)(qbase + 32);

    float lsum = 0.f;
    for (int kt = ky * 8; kt < ky * 8 + 8; ++kt) {
        const int key0 = kt * 64;
        const bf16* kbase = Kp + (size_t)(b * S_LEN + key0 + l15) * KVD + g * DKH + lhi * 8;
#pragma unroll
        for (int nt = 0; nt < 4; ++nt) {
            bf16x8 k0 = *(const bf16x8_a*)(kbase + (size_t)nt * 16 * KVD);
            bf16x8 k1 = *(const bf16x8_a*)(kbase + (size_t)nt * 16 * KVD + 32);
            f32x4 a = {0.f, 0.f, 0.f, 0.f};
            a = __builtin_amdgcn_mfma_f32_16x16x32_bf16(k0, aq0, a, 0, 0, 0);
            a = __builtin_amdgcn_mfma_f32_16x16x32_bf16(k1, aq1, a, 0, 0, 0);
            lsum += __builtin_exp2f(a[0] * SCALE_LOG2E) + __builtin_exp2f(a[1] * SCALE_LOG2E) +
                    __builtin_exp2f(a[2] * SCALE_LOG2E) + __builtin_exp2f(a[3] * SCALE_LOG2E);
        }
    }
    lsum += __shfl_xor(lsum, 16, 64);
    lsum += __shfl_xor(lsum, 32, 64);
    if (lane < 16)
        part[(size_t)ky * (2 * NH * S_LEN) + (size_t)bh * S_LEN + qrow0 + lane] = lsum;
}

// ---------------- main attention kernel ----------------
// grid (B*NH*(S/64), 2 key-halves); block 256 = 4 waves x 16 q-rows.
// Single pass: probs (vectorized f32x4 stores) + PV into fp32 ctx partials.
__global__ __launch_bounds__(256) void attn_main(const bf16* __restrict__ Qp,
                                                 const bf16* __restrict__ Kp,
                                                 const bf16* __restrict__ VT,
                                                 const float* __restrict__ part,
                                                 float* __restrict__ attn_out,
                                                 float* __restrict__ ctxp) {
    __shared__ bf16 plds[4][1024];  // per-wave 16x64 bf16, XOR-swizzled
    const int bh = blockIdx.x >> 5;
    const int qt = blockIdx.x & 31;
    const int kh = blockIdx.y;
    const int h = bh & (NH - 1), b = bh >> 4, g = h >> 2;
    const int wave = threadIdx.x >> 6, lane = threadIdx.x & 63;
    const int l15 = lane & 15, lhi = lane >> 4;
    const int qrow0 = qt * 64 + wave * 16;

    const size_t ridx = (size_t)bh * S_LEN + qrow0 + l15;
    const int NR = 2 * NH * S_LEN;
    float dsum = part[ridx] + part[NR + ridx] + part[2 * (size_t)NR + ridx] +
                 part[3 * (size_t)NR + ridx];
    const float rinv = 1.0f / dsum;

    const bf16* qbase = Qp + (size_t)(b * S_LEN + qrow0 + l15) * DMODEL + h * DKH + lhi * 8;
    bf16x8 aq0 = *(const bf16x8_a*)qbase;
    bf16x8 aq1 = *(const bf16x8_a*)(qbase + 32);

    f32x4 cacc[4] = {};
    float* arow = attn_out + ridx * S_LEN;  // this lane's q-row
    char* pl = (char*)&plds[wave][0];
    const int swz = (l15 & 7) << 4;
    const bf16* vb0 = VT + (size_t)(b * NKVH + g) * DKH * S_LEN + lhi * 8;

    for (int kt = kh * 16; kt < kh * 16 + 16; ++kt) {
        const int key0 = kt * 64;
        const bf16* kbase = Kp + (size_t)(b * S_LEN + key0 + l15) * KVD + g * DKH + lhi * 8;
        // swapped QK^T: D row = key, col = q(lane&15)
        f32x4 s[4];
#pragma unroll
        for (int nt = 0; nt < 4; ++nt) {
            bf16x8 k0 = *(const bf16x8_a*)(kbase + (size_t)nt * 16 * KVD);
            bf16x8 k1 = *(const bf16x8_a*)(kbase + (size_t)nt * 16 * KVD + 32);
            f32x4 a = {0.f, 0.f, 0.f, 0.f};
            a = __builtin_amdgcn_mfma_f32_16x16x32_bf16(k0, aq0, a, 0, 0, 0);
            a = __builtin_amdgcn_mfma_f32_16x16x32_bf16(k1, aq1, a, 0, 0, 0);
            s[nt] = a;
        }
        // probs: 4 consecutive keys per reg -> one dwordx4 store per nt
#pragma unroll
        for (int nt = 0; nt < 4; ++nt) {
            f32x4 p4;
#pragma unroll
            for (int j = 0; j < 4; ++j)
                p4[j] = __builtin_exp2f(s[nt][j] * SCALE_LOG2E) * rinv;
            *(f32x4g*)(arow + key0 + nt * 16 + lhi * 4) = p4;
            bf16x4 pb;
#pragma unroll
            for (int j = 0; j < 4; ++j) pb[j] = (bf16)p4[j];
            *(bf16x4_a*)(pl + ((l15 * 128 + nt * 32 + lhi * 8) ^ swz)) = pb;
        }
        // P A-frags: row = q (lane&15), k = key chunk
        bf16x8 ap0 = *(const bf16x8_a*)(pl + ((l15 * 128 + lhi * 16) ^ swz));
        bf16x8 ap1 = *(const bf16x8_a*)(pl + ((l15 * 128 + 64 + lhi * 16) ^ swz));
        const bf16* vbase = vb0 + key0;
#pragma unroll
        for (int nt = 0; nt < 4; ++nt) {
            bf16x8 v0 = *(const bf16x8_a*)(vbase + (size_t)(nt * 16 + l15) * S_LEN);
            bf16x8 v1 = *(const bf16x8_a*)(vbase + (size_t)(nt * 16 + l15) * S_LEN + 32);
            cacc[nt] = __builtin_amdgcn_mfma_f32_16x16x32_bf16(ap0, v0, cacc[nt], 0, 0, 0);
            cacc[nt] = __builtin_amdgcn_mfma_f32_16x16x32_bf16(ap1, v1, cacc[nt], 0, 0, 0);
        }
    }
    // fp32 ctx partial: row = qrow0 + lhi*4+j, col = h*64 + nt*16 + l15
    float* cp = ctxp + (size_t)kh * ((size_t)2 * S_LEN * DMODEL);
#pragma unroll
    for (int nt = 0; nt < 4; ++nt)
#pragma unroll
        for (int j = 0; j < 4; ++j) {
            int row = qrow0 + lhi * 4 + j;
            cp[(size_t)(b * S_LEN + row) * DMODEL + h * DKH + nt * 16 + l15] = cacc[nt][j];
        }
}

// ---------------- ctx partial combine: bf16(c0+c1) ----------------
__global__ __launch_bounds__(256) void ctx_combine(const float* __restrict__ c,
                                                   bf16* __restrict__ out, int n4) {
    const int NP = 2 * S_LEN * DMODEL / 4;  // f32x4 count per partial
    int stride = gridDim.x * blockDim.x;
    for (int i = blockIdx.x * blockDim.x + threadIdx.x; i < n4; i += stride) {
        f32x4g a = ((const f32x4g*)c)[i];
        f32x4g d = ((const f32x4g*)c)[NP + i];
        bf16x4 o;
#pragma unroll
        for (int j = 0; j < 4; ++j) o[j] = (bf16)(a[j] + d[j]);
        ((bf16x4*)out)[i] = o;
    }
}

extern "C" void kernel_launch(void* const* d_in, const int* in_sizes, int n_in,
                              void* d_out, int out_size, void* d_ws, size_t ws_size,
                              hipStream_t stream) {
    const float* query = (const float*)d_in[0];
    const float* key_i = (const float*)d_in[1];
    const float* value = (const float*)d_in[2];
    const float* Wq = (const float*)d_in[3];
    const float* bq = (const float*)d_in[4];
    const float* Wk = (const float*)d_in[5];
    const float* bk = (const float*)d_in[6];
    const float* Wv = (const float*)d_in[7];
    const float* bv = (const float*)d_in[8];
    const float* Wo = (const float*)d_in[9];
    const float* bo = (const float*)d_in[10];

    char* ws = (char*)d_ws;
    // layout (MB offsets). Lifetime reuse:
    //  [0,16)   qx(0-8)+kx(8-16)        -> ctxp half 0 (fp32, 16MB) after K-gemm
    //  [16,32)  vx(16-24)+free(24-32)   -> ctxp half 1 after V-gemm
    //  [32,34)  wqx                     -> denom partials (1MB) after Q-gemm
    bf16* qx = (bf16*)(ws + 0);
    bf16* kx = (bf16*)(ws + ((size_t)8 << 20));
    bf16* vx = (bf16*)(ws + ((size_t)16 << 20));
    bf16* wqx = (bf16*)(ws + ((size_t)32 << 20));
    bf16* wkx = (bf16*)(ws + ((size_t)34 << 20));
    bf16* wvx = (bf16*)(ws + ((size_t)34 << 20) + ((size_t)512 << 10));
    bf16* wox = (bf16*)(ws + ((size_t)35 << 20));
    bf16* Qp = (bf16*)(ws + ((size_t)37 << 20));
    bf16* Kp = (bf16*)(ws + ((size_t)45 << 20));
    bf16* Vp = (bf16*)(ws + ((size_t)47 << 20));
    bf16* VT = (bf16*)(ws + ((size_t)49 << 20));
    bf16* ctxb = (bf16*)(ws + ((size_t)51 << 20));
    float* part = (float*)(ws + ((size_t)32 << 20));
    float* ctxp = (float*)ws;

    const int BS = 2 * S_LEN;  // 4096 rows

    cast_bf16<<<1024, 256, 0, stream>>>(query, qx, BS * DMODEL / 4);
    cast_bf16<<<1024, 256, 0, stream>>>(key_i, kx, BS * DMODEL / 4);
    cast_bf16<<<1024, 256, 0, stream>>>(value, vx, BS * DMODEL / 4);
    cast_bf16<<<1024, 256, 0, stream>>>(Wq, wqx, DMODEL * DMODEL / 4);
    cast_bf16<<<256, 256, 0, stream>>>(Wk, wkx, KVD * DMODEL / 4);
    cast_bf16<<<256, 256, 0, stream>>>(Wv, wvx, KVD * DMODEL / 4);
    cast_bf16<<<1024, 256, 0, stream>>>(Wo, wox, DMODEL * DMODEL / 4);

    gemm_bt<0><<<dim3(32, 8), 256, 0, stream>>>(qx, wqx, bq, Qp, BS, DMODEL, DMODEL);
    gemm_bt<0><<<dim3(32, 2), 256, 0, stream>>>(kx, wkx, bk, Kp, BS, KVD, DMODEL);
    gemm_bt<0><<<dim3(32, 2), 256, 0, stream>>>(vx, wvx, bv, Vp, BS, KVD, DMODEL);

    vtrans<<<dim3(32, 8), 256, 0, stream>>>(Vp, VT);

    float* attn_out = (float*)d_out + (size_t)BS * DMODEL;
    attn_denom<<<dim3(2 * NH * (S_LEN / 64), 4), 256, 0, stream>>>(Qp, Kp, part);
    attn_main<<<dim3(2 * NH * (S_LEN / 64), 2), 256, 0, stream>>>(Qp, Kp, VT, part, attn_out,
                                                                  ctxp);
    ctx_combine<<<2048, 256, 0, stream>>>(ctxp, ctxb, BS * DMODEL / 4);

    gemm_bt<1><<<dim3(32, 8), 256, 0, stream>>>(ctxb, wox, bo, (float*)d_out, BS, DMODEL, DMODEL);
}

// Round 3
// 365.426 us; speedup vs baseline: 1.5154x; 1.5154x over previous
//
#include <hip/hip_runtime.h>

#define S_LEN 2048
#define DMODEL 1024
#define NH 16
#define NKVH 4
#define DKH 64
#define KVD 256
#define SCALE_LOG2E 0.18033688f  // (1/sqrt(64)) * log2(e)

typedef __bf16 bf16;
typedef bf16  bf16x8 __attribute__((ext_vector_type(8)));
typedef bf16  bf16x4 __attribute__((ext_vector_type(4)));
typedef float f32x4  __attribute__((ext_vector_type(4)));
typedef bf16x8 bf16x8_a __attribute__((may_alias));
typedef bf16x4 bf16x4_a __attribute__((may_alias));
typedef float f32x4g __attribute__((ext_vector_type(4), may_alias));

__device__ __forceinline__ void gll16(const bf16* g, bf16* l) {
    __builtin_amdgcn_global_load_lds(
        (const __attribute__((address_space(1))) void*)g,
        (__attribute__((address_space(3))) void*)l, 16, 0, 0);
}

// ---------------- fp32 -> bf16 cast (vectorized) ----------------
__global__ __launch_bounds__(256) void cast_bf16(const float* __restrict__ in,
                                                 bf16* __restrict__ out, int n4) {
    int stride = gridDim.x * blockDim.x;
    for (int i = blockIdx.x * blockDim.x + threadIdx.x; i < n4; i += stride) {
        f32x4g v = ((const f32x4g*)in)[i];
        bf16x4 o;
        o[0] = (bf16)v[0]; o[1] = (bf16)v[1]; o[2] = (bf16)v[2]; o[3] = (bf16)v[3];
        ((bf16x4*)out)[i] = o;
    }
}

// ---------------- NT GEMM: C[m][n] = sum_k A[m][k]*Bw[n][k] + bias[n] ----------------
template <int OUTF32>
__global__ __launch_bounds__(256) void gemm_bt(const bf16* __restrict__ A,
                                               const bf16* __restrict__ Bw,
                                               const float* __restrict__ bias,
                                               void* __restrict__ Cout,
                                               int M, int N, int K) {
    __shared__ bf16 As[4096];  // 128 x 32
    __shared__ bf16 Bs[4096];
    const int bm = blockIdx.x, bn = blockIdx.y;
    const int tid = threadIdx.x, wave = tid >> 6, lane = tid & 63;
    const int l15 = lane & 15, lhi = lane >> 4;
    const int wr = (wave >> 1) * 64, wc = (wave & 1) * 64;
    f32x4 acc[4][4] = {};
    const size_t arow0 = (size_t)bm * 128 * K;
    const size_t brow0 = (size_t)bn * 128 * K;

    for (int kt = 0; kt < K; kt += 32) {
#pragma unroll
        for (int i = 0; i < 2; ++i) {
            int base = i * 2048 + wave * 512;
            int flat = base + lane * 8;
            int r = flat >> 5, c = flat & 31;
            gll16(A + arow0 + (size_t)r * K + kt + c, &As[base]);
            gll16(Bw + brow0 + (size_t)r * K + kt + c, &Bs[base]);
        }
        __syncthreads();
        bf16x8 af[4], bfr[4];
#pragma unroll
        for (int mi = 0; mi < 4; ++mi)
            af[mi] = *(const bf16x8_a*)&As[(wr + mi * 16 + l15) * 32 + lhi * 8];
#pragma unroll
        for (int ni = 0; ni < 4; ++ni)
            bfr[ni] = *(const bf16x8_a*)&Bs[(wc + ni * 16 + l15) * 32 + lhi * 8];
#pragma unroll
        for (int mi = 0; mi < 4; ++mi)
#pragma unroll
            for (int ni = 0; ni < 4; ++ni)
                acc[mi][ni] = __builtin_amdgcn_mfma_f32_16x16x32_bf16(
                    af[mi], bfr[ni], acc[mi][ni], 0, 0, 0);
        __syncthreads();
    }
#pragma unroll
    for (int mi = 0; mi < 4; ++mi)
#pragma unroll
        for (int ni = 0; ni < 4; ++ni)
#pragma unroll
            for (int j = 0; j < 4; ++j) {
                int row = bm * 128 + wr + mi * 16 + lhi * 4 + j;
                int col = bn * 128 + wc + ni * 16 + l15;
                float v = acc[mi][ni][j] + bias[col];
                if (OUTF32)
                    ((float*)Cout)[(size_t)row * N + col] = v;
                else
                    ((bf16*)Cout)[(size_t)row * N + col] = (bf16)v;
            }
}

// ---------------- V transpose: Vp[b*2048+s][g*64+d] -> VT[b][g][d][s] ----------------
__global__ __launch_bounds__(256) void vtrans(const bf16* __restrict__ V,
                                              bf16* __restrict__ VT) {
    __shared__ bf16 t[64][65];
    const int s0 = blockIdx.x * 64;
    const int bg = blockIdx.y;
    const int b = bg >> 2, g = bg & 3;
#pragma unroll
    for (int i = 0; i < 16; ++i) {
        int flat = threadIdx.x + i * 256;
        int r = flat >> 6, c = flat & 63;
        t[c][r] = V[(size_t)(b * S_LEN + s0 + r) * KVD + g * DKH + c];
    }
    __syncthreads();
#pragma unroll
    for (int i = 0; i < 16; ++i) {
        int flat = threadIdx.x + i * 256;
        int d = flat >> 6, si = flat & 63;
        VT[((size_t)bg * DKH + d) * S_LEN + s0 + si] = t[d][si];
    }
}

// ---------------- denominator kernel ----------------
// grid (32bh*16qt, 2 key-halves); block 512 = 8 waves x 16 q-rows.
// K tile (64x64) staged to LDS (XOR-swizzled, dbuf) shared by all 8 waves.
__global__ __launch_bounds__(512) void attn_denom(const bf16* __restrict__ Qp,
                                                  const bf16* __restrict__ Kp,
                                                  float* __restrict__ part) {
    __shared__ bf16 Ks[2][4096];
    const int bh = blockIdx.x >> 4;
    const int qt = blockIdx.x & 15;
    const int ky = blockIdx.y;
    const int h = bh & (NH - 1), b = bh >> 4, g = h >> 2;
    const int wave = threadIdx.x >> 6, lane = threadIdx.x & 63;
    const int l15 = lane & 15, lhi = lane >> 4;
    const int qrow0 = qt * 128 + wave * 16;

    const bf16* qbase = Qp + (size_t)(b * S_LEN + qrow0 + l15) * DMODEL + h * DKH + lhi * 8;
    bf16x8 aq0 = *(const bf16x8_a*)qbase;
    bf16x8 aq1 = *(const bf16x8_a*)(qbase + 32);

    // staging: thread covers 16B chunk (row srow, phys chunk lane&7 -> logical scc)
    const int srow = wave * 8 + (lane >> 3);
    const int scc = (lane & 7) ^ ((lane >> 3) & 7);
    const bf16* ksrc = Kp + (size_t)(b * S_LEN + srow) * KVD + g * DKH + scc * 8;

    const int kt0 = ky * 16;
    gll16(ksrc + (size_t)(kt0 * 64) * KVD, &Ks[0][wave * 512]);
    __syncthreads();

    const int sw = (l15 & 7) << 4;
    float lsum = 0.f;
    int buf = 0;
    for (int kt = kt0; kt < kt0 + 16; ++kt) {
        if (kt < kt0 + 15)
            gll16(ksrc + (size_t)((kt + 1) * 64) * KVD, &Ks[buf ^ 1][wave * 512]);
        const char* kc = (const char*)&Ks[buf][0];
#pragma unroll
        for (int nt = 0; nt < 4; ++nt) {
            int rb = (nt * 16 + l15) * 128;
            bf16x8 k0 = *(const bf16x8_a*)(kc + rb + ((lhi * 16) ^ sw));
            bf16x8 k1 = *(const bf16x8_a*)(kc + rb + ((lhi * 16 + 64) ^ sw));
            f32x4 a = {0.f, 0.f, 0.f, 0.f};
            a = __builtin_amdgcn_mfma_f32_16x16x32_bf16(k0, aq0, a, 0, 0, 0);
            a = __builtin_amdgcn_mfma_f32_16x16x32_bf16(k1, aq1, a, 0, 0, 0);
            lsum += __builtin_exp2f(a[0] * SCALE_LOG2E) + __builtin_exp2f(a[1] * SCALE_LOG2E) +
                    __builtin_exp2f(a[2] * SCALE_LOG2E) + __builtin_exp2f(a[3] * SCALE_LOG2E);
        }
        __syncthreads();
        buf ^= 1;
    }
    lsum += __shfl_xor(lsum, 16, 64);
    lsum += __shfl_xor(lsum, 32, 64);
    if (lane < 16)
        part[(size_t)ky * (2 * NH * S_LEN) + (size_t)bh * S_LEN + qrow0 + lane] = lsum;
}

// ---------------- main attention kernel ----------------
// grid 32bh*16qt; block 512 = 8 waves x 16 q-rows. All 32 K-tiles per block.
// K & V tiles staged to LDS (XOR-swizzled, dbuf, gll16) shared by 8 waves.
__global__ __launch_bounds__(512) void attn_main(const bf16* __restrict__ Qp,
                                                 const bf16* __restrict__ Kp,
                                                 const bf16* __restrict__ VT,
                                                 const float* __restrict__ part,
                                                 float* __restrict__ attn_out,
                                                 bf16* __restrict__ ctx) {
    __shared__ bf16 Ks[2][4096];
    __shared__ bf16 Vs[2][4096];
    __shared__ bf16 Ps[8][1024];  // per-wave 16x64, XOR-swizzled
    const int bh = blockIdx.x >> 4;
    const int qt = blockIdx.x & 15;
    const int h = bh & (NH - 1), b = bh >> 4, g = h >> 2;
    const int wave = threadIdx.x >> 6, lane = threadIdx.x & 63;
    const int l15 = lane & 15, lhi = lane >> 4;
    const int qrow0 = qt * 128 + wave * 16;

    const size_t ridx = (size_t)bh * S_LEN + qrow0 + l15;
    const int NR = 2 * NH * S_LEN;
    const float rinv = 1.0f / (part[ridx] + part[NR + ridx]);

    const bf16* qbase = Qp + (size_t)(b * S_LEN + qrow0 + l15) * DMODEL + h * DKH + lhi * 8;
    bf16x8 aq0 = *(const bf16x8_a*)qbase;
    bf16x8 aq1 = *(const bf16x8_a*)(qbase + 32);

    const int srow = wave * 8 + (lane >> 3);
    const int scc = (lane & 7) ^ ((lane >> 3) & 7);
    const bf16* ksrc = Kp + (size_t)(b * S_LEN + srow) * KVD + g * DKH + scc * 8;
    const bf16* vsrc = VT + ((size_t)(b * NKVH + g) * DKH + srow) * S_LEN + scc * 8;

    gll16(ksrc, &Ks[0][wave * 512]);
    gll16(vsrc, &Vs[0][wave * 512]);
    __syncthreads();

    f32x4 cacc[4] = {};
    float* arow = attn_out + ridx * S_LEN;
    char* pl = (char*)&Ps[wave][0];
    const int sw = (l15 & 7) << 4;
    int buf = 0;
    for (int kt = 0; kt < 32; ++kt) {
        const int key0 = kt * 64;
        if (kt < 31) {
            gll16(ksrc + (size_t)(key0 + 64) * KVD, &Ks[buf ^ 1][wave * 512]);
            gll16(vsrc + key0 + 64, &Vs[buf ^ 1][wave * 512]);
        }
        // QK^T (swapped): D row=key, col=q
        const char* kc = (const char*)&Ks[buf][0];
        f32x4 s[4];
#pragma unroll
        for (int nt = 0; nt < 4; ++nt) {
            int rb = (nt * 16 + l15) * 128;
            bf16x8 k0 = *(const bf16x8_a*)(kc + rb + ((lhi * 16) ^ sw));
            bf16x8 k1 = *(const bf16x8_a*)(kc + rb + ((lhi * 16 + 64) ^ sw));
            f32x4 a = {0.f, 0.f, 0.f, 0.f};
            a = __builtin_amdgcn_mfma_f32_16x16x32_bf16(k0, aq0, a, 0, 0, 0);
            a = __builtin_amdgcn_mfma_f32_16x16x32_bf16(k1, aq1, a, 0, 0, 0);
            s[nt] = a;
        }
        // probs: nontemporal dwordx4 store + P -> per-wave LDS (bf16)
#pragma unroll
        for (int nt = 0; nt < 4; ++nt) {
            f32x4 p4;
#pragma unroll
            for (int j = 0; j < 4; ++j)
                p4[j] = __builtin_exp2f(s[nt][j] * SCALE_LOG2E) * rinv;
            __builtin_nontemporal_store(p4, (f32x4g*)(arow + key0 + nt * 16 + lhi * 4));
            bf16x4 pb;
#pragma unroll
            for (int j = 0; j < 4; ++j) pb[j] = (bf16)p4[j];
            *(bf16x4_a*)(pl + ((l15 * 128 + nt * 32 + lhi * 8) ^ sw)) = pb;
        }
        bf16x8 ap0 = *(const bf16x8_a*)(pl + ((l15 * 128 + lhi * 16) ^ sw));
        bf16x8 ap1 = *(const bf16x8_a*)(pl + ((l15 * 128 + 64 + lhi * 16) ^ sw));
        const char* vc = (const char*)&Vs[buf][0];
#pragma unroll
        for (int nt = 0; nt < 4; ++nt) {
            int rb = (nt * 16 + l15) * 128;
            bf16x8 v0 = *(const bf16x8_a*)(vc + rb + ((lhi * 16) ^ sw));
            bf16x8 v1 = *(const bf16x8_a*)(vc + rb + ((lhi * 16 + 64) ^ sw));
            cacc[nt] = __builtin_amdgcn_mfma_f32_16x16x32_bf16(ap0, v0, cacc[nt], 0, 0, 0);
            cacc[nt] = __builtin_amdgcn_mfma_f32_16x16x32_bf16(ap1, v1, cacc[nt], 0, 0, 0);
        }
        __syncthreads();
        buf ^= 1;
    }
    // ctx write: row = qrow0+lhi*4+j, col = h*64 + nt*16 + l15
#pragma unroll
    for (int nt = 0; nt < 4; ++nt)
#pragma unroll
        for (int j = 0; j < 4; ++j) {
            int row = qrow0 + lhi * 4 + j;
            ctx[(size_t)(b * S_LEN + row) * DMODEL + h * DKH + nt * 16 + l15] =
                (bf16)cacc[nt][j];
        }
}

extern "C" void kernel_launch(void* const* d_in, const int* in_sizes, int n_in,
                              void* d_out, int out_size, void* d_ws, size_t ws_size,
                              hipStream_t stream) {
    const float* query = (const float*)d_in[0];
    const float* key_i = (const float*)d_in[1];
    const float* value = (const float*)d_in[2];
    const float* Wq = (const float*)d_in[3];
    const float* bq = (const float*)d_in[4];
    const float* Wk = (const float*)d_in[5];
    const float* bk = (const float*)d_in[6];
    const float* Wv = (const float*)d_in[7];
    const float* bv = (const float*)d_in[8];
    const float* Wo = (const float*)d_in[9];
    const float* bo = (const float*)d_in[10];

    char* ws = (char*)d_ws;
    bf16* qx = (bf16*)(ws + 0);
    bf16* kx = (bf16*)(ws + ((size_t)8 << 20));
    bf16* vx = (bf16*)(ws + ((size_t)16 << 20));
    bf16* wqx = (bf16*)(ws + ((size_t)32 << 20));
    bf16* wkx = (bf16*)(ws + ((size_t)34 << 20));
    bf16* wvx = (bf16*)(ws + ((size_t)34 << 20) + ((size_t)512 << 10));
    bf16* wox = (bf16*)(ws + ((size_t)35 << 20));
    bf16* Qp = (bf16*)(ws + ((size_t)37 << 20));
    bf16* Kp = (bf16*)(ws + ((size_t)45 << 20));
    bf16* Vp = (bf16*)(ws + ((size_t)47 << 20));
    bf16* VT = (bf16*)(ws + ((size_t)49 << 20));
    bf16* ctxb = (bf16*)(ws + ((size_t)51 << 20));
    float* part = (float*)(ws + ((size_t)32 << 20));  // reuses wqx slot (dead after Q-gemm)

    const int BS = 2 * S_LEN;  // 4096 rows

    cast_bf16<<<1024, 256, 0, stream>>>(query, qx, BS * DMODEL / 4);
    cast_bf16<<<1024, 256, 0, stream>>>(key_i, kx, BS * DMODEL / 4);
    cast_bf16<<<1024, 256, 0, stream>>>(value, vx, BS * DMODEL / 4);
    cast_bf16<<<1024, 256, 0, stream>>>(Wq, wqx, DMODEL * DMODEL / 4);
    cast_bf16<<<256, 256, 0, stream>>>(Wk, wkx, KVD * DMODEL / 4);
    cast_bf16<<<256, 256, 0, stream>>>(Wv, wvx, KVD * DMODEL / 4);
    cast_bf16<<<1024, 256, 0, stream>>>(Wo, wox, DMODEL * DMODEL / 4);

    gemm_bt<0><<<dim3(32, 8), 256, 0, stream>>>(qx, wqx, bq, Qp, BS, DMODEL, DMODEL);
    gemm_bt<0><<<dim3(32, 2), 256, 0, stream>>>(kx, wkx, bk, Kp, BS, KVD, DMODEL);
    gemm_bt<0><<<dim3(32, 2), 256, 0, stream>>>(vx, wvx, bv, Vp, BS, KVD, DMODEL);

    vtrans<<<dim3(32, 8), 256, 0, stream>>>(Vp, VT);

    float* attn_out = (float*)d_out + (size_t)BS * DMODEL;
    attn_denom<<<dim3(512, 2), 512, 0, stream>>>(Qp, Kp, part);
    attn_main<<<512, 512, 0, stream>>>(Qp, Kp, VT, part, attn_out, ctxb);

    gemm_bt<1><<<dim3(32, 8), 256, 0, stream>>>(ctxb, wox, bo, (float*)d_out, BS, DMODEL, DMODEL);
}

// Round 4
// 350.864 us; speedup vs baseline: 1.5783x; 1.0415x over previous
//
#include <hip/hip_runtime.h>

#define S_LEN 2048
#define DMODEL 1024
#define NH 16
#define NKVH 4
#define DKH 64
#define KVD 256
#define SCALE_LOG2E 0.18033688f  // (1/sqrt(64)) * log2(e)

typedef __bf16 bf16;
typedef bf16  bf16x8 __attribute__((ext_vector_type(8)));
typedef bf16  bf16x4 __attribute__((ext_vector_type(4)));
typedef float f32x4  __attribute__((ext_vector_type(4)));
typedef bf16x8 bf16x8_a __attribute__((may_alias));
typedef bf16x4 bf16x4_a __attribute__((may_alias));
typedef float f32x4g __attribute__((ext_vector_type(4), may_alias));

// counted waitcnt: stores/prefetches stay in flight across barriers (T3/T4)
#define VWAIT(N)                                             \
    do {                                                     \
        asm volatile("s_waitcnt vmcnt(" #N ")" ::: "memory");\
        __builtin_amdgcn_sched_barrier(0);                   \
    } while (0)

__device__ __forceinline__ void gll16(const bf16* g, bf16* l) {
    __builtin_amdgcn_global_load_lds(
        (const __attribute__((address_space(1))) void*)g,
        (__attribute__((address_space(3))) void*)l, 16, 0, 0);
}

// ---------------- fused fp32 -> bf16 casts ----------------
__global__ __launch_bounds__(256) void cast3_bf16(const float* __restrict__ a,
                                                  const float* __restrict__ b,
                                                  const float* __restrict__ c,
                                                  bf16* __restrict__ oa, bf16* __restrict__ ob,
                                                  bf16* __restrict__ oc, int n4) {
    const float* src = blockIdx.y == 0 ? a : blockIdx.y == 1 ? b : c;
    bf16* dst = blockIdx.y == 0 ? oa : blockIdx.y == 1 ? ob : oc;
    int stride = gridDim.x * blockDim.x;
    for (int i = blockIdx.x * blockDim.x + threadIdx.x; i < n4; i += stride) {
        f32x4g v = ((const f32x4g*)src)[i];
        bf16x4 o;
        o[0] = (bf16)v[0]; o[1] = (bf16)v[1]; o[2] = (bf16)v[2]; o[3] = (bf16)v[3];
        ((bf16x4*)dst)[i] = o;
    }
}

__global__ __launch_bounds__(256) void cast2_bf16(const float* __restrict__ a,
                                                  const float* __restrict__ b,
                                                  bf16* __restrict__ oa, bf16* __restrict__ ob,
                                                  int n4) {
    const float* src = blockIdx.y == 0 ? a : b;
    bf16* dst = blockIdx.y == 0 ? oa : ob;
    int stride = gridDim.x * blockDim.x;
    for (int i = blockIdx.x * blockDim.x + threadIdx.x; i < n4; i += stride) {
        f32x4g v = ((const f32x4g*)src)[i];
        bf16x4 o;
        o[0] = (bf16)v[0]; o[1] = (bf16)v[1]; o[2] = (bf16)v[2]; o[3] = (bf16)v[3];
        ((bf16x4*)dst)[i] = o;
    }
}

// ---------------- NT GEMM: C[m][n] = sum_k A[m][k]*Bw[n][k] + bias[n] ----------------
template <int OUTF32>
__global__ __launch_bounds__(256) void gemm_bt(const bf16* __restrict__ A,
                                               const bf16* __restrict__ Bw,
                                               const float* __restrict__ bias,
                                               void* __restrict__ Cout,
                                               int M, int N, int K) {
    __shared__ bf16 As[4096];  // 128 x 32
    __shared__ bf16 Bs[4096];
    const int bm = blockIdx.x, bn = blockIdx.y;
    const int tid = threadIdx.x, wave = tid >> 6, lane = tid & 63;
    const int l15 = lane & 15, lhi = lane >> 4;
    const int wr = (wave >> 1) * 64, wc = (wave & 1) * 64;
    f32x4 acc[4][4] = {};
    const size_t arow0 = (size_t)bm * 128 * K;
    const size_t brow0 = (size_t)bn * 128 * K;

    for (int kt = 0; kt < K; kt += 32) {
#pragma unroll
        for (int i = 0; i < 2; ++i) {
            int base = i * 2048 + wave * 512;
            int flat = base + lane * 8;
            int r = flat >> 5, c = flat & 31;
            gll16(A + arow0 + (size_t)r * K + kt + c, &As[base]);
            gll16(Bw + brow0 + (size_t)r * K + kt + c, &Bs[base]);
        }
        __syncthreads();
        bf16x8 af[4], bfr[4];
#pragma unroll
        for (int mi = 0; mi < 4; ++mi)
            af[mi] = *(const bf16x8_a*)&As[(wr + mi * 16 + l15) * 32 + lhi * 8];
#pragma unroll
        for (int ni = 0; ni < 4; ++ni)
            bfr[ni] = *(const bf16x8_a*)&Bs[(wc + ni * 16 + l15) * 32 + lhi * 8];
#pragma unroll
        for (int mi = 0; mi < 4; ++mi)
#pragma unroll
            for (int ni = 0; ni < 4; ++ni)
                acc[mi][ni] = __builtin_amdgcn_mfma_f32_16x16x32_bf16(
                    af[mi], bfr[ni], acc[mi][ni], 0, 0, 0);
        __syncthreads();
    }
#pragma unroll
    for (int mi = 0; mi < 4; ++mi)
#pragma unroll
        for (int ni = 0; ni < 4; ++ni)
#pragma unroll
            for (int j = 0; j < 4; ++j) {
                int row = bm * 128 + wr + mi * 16 + lhi * 4 + j;
                int col = bn * 128 + wc + ni * 16 + l15;
                float v = acc[mi][ni][j] + bias[col];
                if (OUTF32)
                    ((float*)Cout)[(size_t)row * N + col] = v;
                else
                    ((bf16*)Cout)[(size_t)row * N + col] = (bf16)v;
            }
}

// ---------------- V transpose: Vp[b*2048+s][g*64+d] -> VT[b][g][d][s] ----------------
__global__ __launch_bounds__(256) void vtrans(const bf16* __restrict__ V,
                                              bf16* __restrict__ VT) {
    __shared__ bf16 t[64][65];
    const int s0 = blockIdx.x * 64;
    const int bg = blockIdx.y;
    const int b = bg >> 2, g = bg & 3;
#pragma unroll
    for (int i = 0; i < 16; ++i) {
        int flat = threadIdx.x + i * 256;
        int r = flat >> 6, c = flat & 63;
        t[c][r] = V[(size_t)(b * S_LEN + s0 + r) * KVD + g * DKH + c];
    }
    __syncthreads();
#pragma unroll
    for (int i = 0; i < 16; ++i) {
        int flat = threadIdx.x + i * 256;
        int d = flat >> 6, si = flat & 63;
        VT[((size_t)bg * DKH + d) * S_LEN + s0 + si] = t[d][si];
    }
}

// ---------------- fused GQA attention (denom pass + prob/PV pass) ----------------
// grid 512 = bh(32) x qt(16); block 512 = 8 waves x 16 q-rows.
// K/V tiles: 4-deep LDS ring, depth-2 prefetch, counted vmcnt, raw barriers.
__global__ __launch_bounds__(512, 4) void attn_fused2(const bf16* __restrict__ Qp,
                                                      const bf16* __restrict__ Kp,
                                                      const bf16* __restrict__ VT,
                                                      float* __restrict__ attn_out,
                                                      bf16* __restrict__ ctx) {
    __shared__ bf16 Ks[4][4096];  // 32 KB
    __shared__ bf16 Vs[4][4096];  // 32 KB
    __shared__ bf16 Ps[8][1024];  // 16 KB, per-wave 16x64, XOR-swizzled
    const int bh = blockIdx.x >> 4;
    const int qt = blockIdx.x & 15;
    const int h = bh & (NH - 1), b = bh >> 4, g = h >> 2;
    const int wave = threadIdx.x >> 6, lane = threadIdx.x & 63;
    const int l15 = lane & 15, lhi = lane >> 4;
    const int qrow0 = qt * 128 + wave * 16;

    const bf16* qbase = Qp + (size_t)(b * S_LEN + qrow0 + l15) * DMODEL + h * DKH + lhi * 8;
    bf16x8 aq0 = *(const bf16x8_a*)qbase;
    bf16x8 aq1 = *(const bf16x8_a*)(qbase + 32);

    // staging: wave covers 8 rows; source column pre-swizzled (rule #21)
    const int srow = wave * 8 + (lane >> 3);
    const int scc = (lane & 7) ^ ((lane >> 3) & 7);
    const bf16* ksrc = Kp + (size_t)(b * S_LEN + srow) * KVD + g * DKH + scc * 8;
    const bf16* vsrc = VT + ((size_t)(b * NKVH + g) * DKH + srow) * S_LEN + scc * 8;
    const int sw = (l15 & 7) << 4;

    // ================= pass A: softmax denominators =================
    gll16(ksrc, &Ks[0][wave * 512]);
    gll16(ksrc + (size_t)64 * KVD, &Ks[1][wave * 512]);
    VWAIT(1);
    __builtin_amdgcn_s_barrier();

    float lsum = 0.f;
    for (int kt = 0; kt < 32; ++kt) {
        if (kt < 30)
            gll16(ksrc + (size_t)((kt + 2) * 64) * KVD, &Ks[(kt + 2) & 3][wave * 512]);
        const char* kc = (const char*)&Ks[kt & 3][0];
        f32x4 s[4];
        __builtin_amdgcn_s_setprio(1);
#pragma unroll
        for (int nt = 0; nt < 4; ++nt) {
            int rb = (nt * 16 + l15) * 128;
            bf16x8 k0 = *(const bf16x8_a*)(kc + rb + ((lhi * 16) ^ sw));
            bf16x8 k1 = *(const bf16x8_a*)(kc + rb + ((lhi * 16 + 64) ^ sw));
            f32x4 a = {0.f, 0.f, 0.f, 0.f};
            a = __builtin_amdgcn_mfma_f32_16x16x32_bf16(k0, aq0, a, 0, 0, 0);
            a = __builtin_amdgcn_mfma_f32_16x16x32_bf16(k1, aq1, a, 0, 0, 0);
            s[nt] = a;
        }
        __builtin_amdgcn_s_setprio(0);
#pragma unroll
        for (int nt = 0; nt < 4; ++nt)
            lsum += __builtin_exp2f(s[nt][0] * SCALE_LOG2E) +
                    __builtin_exp2f(s[nt][1] * SCALE_LOG2E) +
                    __builtin_exp2f(s[nt][2] * SCALE_LOG2E) +
                    __builtin_exp2f(s[nt][3] * SCALE_LOG2E);
        if (kt < 31) {
            if (kt < 30) { VWAIT(1); } else { VWAIT(0); }
            __builtin_amdgcn_s_barrier();
        }
    }
    lsum += __shfl_xor(lsum, 16, 64);
    lsum += __shfl_xor(lsum, 32, 64);
    const float rinv = 1.0f / lsum;

    // ================= pass B: probs + PV =================
    gll16(ksrc, &Ks[0][wave * 512]);
    gll16(vsrc, &Vs[0][wave * 512]);
    gll16(ksrc + (size_t)64 * KVD, &Ks[1][wave * 512]);
    gll16(vsrc + 64, &Vs[1][wave * 512]);
    VWAIT(2);
    __builtin_amdgcn_s_barrier();

    f32x4 cacc[4] = {};
    float* arow = attn_out + ((size_t)bh * S_LEN + qrow0 + l15) * S_LEN;
    char* pl = (char*)&Ps[wave][0];

    for (int kt = 0; kt < 32; ++kt) {
        const int key0 = kt * 64;
        if (kt < 30) {
            gll16(ksrc + (size_t)((kt + 2) * 64) * KVD, &Ks[(kt + 2) & 3][wave * 512]);
            gll16(vsrc + (kt + 2) * 64, &Vs[(kt + 2) & 3][wave * 512]);
        }
        const char* kc = (const char*)&Ks[kt & 3][0];
        f32x4 s[4];
        __builtin_amdgcn_s_setprio(1);
#pragma unroll
        for (int nt = 0; nt < 4; ++nt) {
            int rb = (nt * 16 + l15) * 128;
            bf16x8 k0 = *(const bf16x8_a*)(kc + rb + ((lhi * 16) ^ sw));
            bf16x8 k1 = *(const bf16x8_a*)(kc + rb + ((lhi * 16 + 64) ^ sw));
            f32x4 a = {0.f, 0.f, 0.f, 0.f};
            a = __builtin_amdgcn_mfma_f32_16x16x32_bf16(k0, aq0, a, 0, 0, 0);
            a = __builtin_amdgcn_mfma_f32_16x16x32_bf16(k1, aq1, a, 0, 0, 0);
            s[nt] = a;
        }
        __builtin_amdgcn_s_setprio(0);
        // probs: nontemporal f32x4 store + bf16 copy into per-wave LDS
#pragma unroll
        for (int nt = 0; nt < 4; ++nt) {
            f32x4 p4;
#pragma unroll
            for (int j = 0; j < 4; ++j)
                p4[j] = __builtin_exp2f(s[nt][j] * SCALE_LOG2E) * rinv;
            __builtin_nontemporal_store(p4, (f32x4g*)(arow + key0 + nt * 16 + lhi * 4));
            bf16x4 pb;
#pragma unroll
            for (int j = 0; j < 4; ++j) pb[j] = (bf16)p4[j];
            *(bf16x4_a*)(pl + ((l15 * 128 + nt * 32 + lhi * 8) ^ sw)) = pb;
        }
        bf16x8 ap0 = *(const bf16x8_a*)(pl + ((l15 * 128 + lhi * 16) ^ sw));
        bf16x8 ap1 = *(const bf16x8_a*)(pl + ((l15 * 128 + 64 + lhi * 16) ^ sw));
        const char* vc = (const char*)&Vs[kt & 3][0];
        __builtin_amdgcn_s_setprio(1);
#pragma unroll
        for (int nt = 0; nt < 4; ++nt) {
            int rb = (nt * 16 + l15) * 128;
            bf16x8 v0 = *(const bf16x8_a*)(vc + rb + ((lhi * 16) ^ sw));
            bf16x8 v1 = *(const bf16x8_a*)(vc + rb + ((lhi * 16 + 64) ^ sw));
            cacc[nt] = __builtin_amdgcn_mfma_f32_16x16x32_bf16(ap0, v0, cacc[nt], 0, 0, 0);
            cacc[nt] = __builtin_amdgcn_mfma_f32_16x16x32_bf16(ap1, v1, cacc[nt], 0, 0, 0);
        }
        __builtin_amdgcn_s_setprio(0);
        if (kt < 31) {
            // drain stage(kt+1) only; prob stores + stage(kt+2) stay in flight
            if (kt == 0) { VWAIT(6); }
            else if (kt < 30) { VWAIT(10); }
            else { VWAIT(8); }
            __builtin_amdgcn_s_barrier();
        }
    }
    // ctx write: row = qrow0+lhi*4+j, col = h*64 + nt*16 + l15
#pragma unroll
    for (int nt = 0; nt < 4; ++nt)
#pragma unroll
        for (int j = 0; j < 4; ++j) {
            int row = qrow0 + lhi * 4 + j;
            ctx[(size_t)(b * S_LEN + row) * DMODEL + h * DKH + nt * 16 + l15] =
                (bf16)cacc[nt][j];
        }
}

extern "C" void kernel_launch(void* const* d_in, const int* in_sizes, int n_in,
                              void* d_out, int out_size, void* d_ws, size_t ws_size,
                              hipStream_t stream) {
    const float* query = (const float*)d_in[0];
    const float* key_i = (const float*)d_in[1];
    const float* value = (const float*)d_in[2];
    const float* Wq = (const float*)d_in[3];
    const float* bq = (const float*)d_in[4];
    const float* Wk = (const float*)d_in[5];
    const float* bk = (const float*)d_in[6];
    const float* Wv = (const float*)d_in[7];
    const float* bv = (const float*)d_in[8];
    const float* Wo = (const float*)d_in[9];
    const float* bo = (const float*)d_in[10];

    char* ws = (char*)d_ws;
    bf16* qx = (bf16*)(ws + 0);
    bf16* kx = (bf16*)(ws + ((size_t)8 << 20));
    bf16* vx = (bf16*)(ws + ((size_t)16 << 20));
    bf16* wqx = (bf16*)(ws + ((size_t)32 << 20));
    bf16* wkx = (bf16*)(ws + ((size_t)34 << 20));
    bf16* wvx = (bf16*)(ws + ((size_t)34 << 20) + ((size_t)512 << 10));
    bf16* wox = (bf16*)(ws + ((size_t)35 << 20));
    bf16* Qp = (bf16*)(ws + ((size_t)37 << 20));
    bf16* Kp = (bf16*)(ws + ((size_t)45 << 20));
    bf16* Vp = (bf16*)(ws + ((size_t)47 << 20));
    bf16* VT = (bf16*)(ws + ((size_t)49 << 20));
    bf16* ctxb = (bf16*)(ws + ((size_t)51 << 20));

    const int BS = 2 * S_LEN;  // 4096 rows

    cast3_bf16<<<dim3(1024, 3), 256, 0, stream>>>(query, key_i, value, qx, kx, vx,
                                                  BS * DMODEL / 4);
    cast2_bf16<<<dim3(1024, 2), 256, 0, stream>>>(Wq, Wo, wqx, wox, DMODEL * DMODEL / 4);
    cast2_bf16<<<dim3(256, 2), 256, 0, stream>>>(Wk, Wv, wkx, wvx, KVD * DMODEL / 4);

    gemm_bt<0><<<dim3(32, 8), 256, 0, stream>>>(qx, wqx, bq, Qp, BS, DMODEL, DMODEL);
    gemm_bt<0><<<dim3(32, 2), 256, 0, stream>>>(kx, wkx, bk, Kp, BS, KVD, DMODEL);
    gemm_bt<0><<<dim3(32, 2), 256, 0, stream>>>(vx, wvx, bv, Vp, BS, KVD, DMODEL);

    vtrans<<<dim3(32, 8), 256, 0, stream>>>(Vp, VT);

    float* attn_out = (float*)d_out + (size_t)BS * DMODEL;
    attn_fused2<<<512, 512, 0, stream>>>(Qp, Kp, VT, attn_out, ctxb);

    gemm_bt<1><<<dim3(32, 8), 256, 0, stream>>>(ctxb, wox, bo, (float*)d_out, BS, DMODEL, DMODEL);
}

// Round 5
// 348.386 us; speedup vs baseline: 1.5895x; 1.0071x over previous
//
#include <hip/hip_runtime.h>

#define S_LEN 2048
#define DMODEL 1024
#define NH 16
#define NKVH 4
#define DKH 64
#define KVD 256
#define SCALE_LOG2E 0.18033688f  // (1/sqrt(64)) * log2(e)

typedef __bf16 bf16;
typedef bf16  bf16x8 __attribute__((ext_vector_type(8)));
typedef bf16  bf16x4 __attribute__((ext_vector_type(4)));
typedef float f32x4  __attribute__((ext_vector_type(4)));
typedef bf16x8 bf16x8_a __attribute__((may_alias));
typedef bf16x4 bf16x4_a __attribute__((may_alias));
typedef float f32x4g __attribute__((ext_vector_type(4), may_alias));

#define VWAIT(N)                                             \
    do {                                                     \
        asm volatile("s_waitcnt vmcnt(" #N ")" ::: "memory");\
        __builtin_amdgcn_sched_barrier(0);                   \
    } while (0)

__device__ __forceinline__ void gll16(const bf16* g, bf16* l) {
    __builtin_amdgcn_global_load_lds(
        (const __attribute__((address_space(1))) void*)g,
        (__attribute__((address_space(3))) void*)l, 16, 0, 0);
}

// ---------------- fused fp32 -> bf16 casts ----------------
__global__ __launch_bounds__(256) void cast3_bf16(const float* __restrict__ a,
                                                  const float* __restrict__ b,
                                                  const float* __restrict__ c,
                                                  bf16* __restrict__ oa, bf16* __restrict__ ob,
                                                  bf16* __restrict__ oc, int n4) {
    const float* src = blockIdx.y == 0 ? a : blockIdx.y == 1 ? b : c;
    bf16* dst = blockIdx.y == 0 ? oa : blockIdx.y == 1 ? ob : oc;
    int stride = gridDim.x * blockDim.x;
    for (int i = blockIdx.x * blockDim.x + threadIdx.x; i < n4; i += stride) {
        f32x4g v = ((const f32x4g*)src)[i];
        bf16x4 o;
        o[0] = (bf16)v[0]; o[1] = (bf16)v[1]; o[2] = (bf16)v[2]; o[3] = (bf16)v[3];
        ((bf16x4*)dst)[i] = o;
    }
}

__global__ __launch_bounds__(256) void cast2_bf16(const float* __restrict__ a,
                                                  const float* __restrict__ b,
                                                  bf16* __restrict__ oa, bf16* __restrict__ ob,
                                                  int n4) {
    const float* src = blockIdx.y == 0 ? a : b;
    bf16* dst = blockIdx.y == 0 ? oa : ob;
    int stride = gridDim.x * blockDim.x;
    for (int i = blockIdx.x * blockDim.x + threadIdx.x; i < n4; i += stride) {
        f32x4g v = ((const f32x4g*)src)[i];
        bf16x4 o;
        o[0] = (bf16)v[0]; o[1] = (bf16)v[1]; o[2] = (bf16)v[2]; o[3] = (bf16)v[3];
        ((bf16x4*)dst)[i] = o;
    }
}

// ---------------- NT GEMM: C[m][n] = sum_k A[m][k]*Bw[n][k] + bias[n] ----------------
template <int OUTF32>
__global__ __launch_bounds__(256) void gemm_bt(const bf16* __restrict__ A,
                                               const bf16* __restrict__ Bw,
                                               const float* __restrict__ bias,
                                               void* __restrict__ Cout,
                                               int M, int N, int K) {
    __shared__ bf16 As[4096];  // 128 x 32
    __shared__ bf16 Bs[4096];
    const int bm = blockIdx.x, bn = blockIdx.y;
    const int tid = threadIdx.x, wave = tid >> 6, lane = tid & 63;
    const int l15 = lane & 15, lhi = lane >> 4;
    const int wr = (wave >> 1) * 64, wc = (wave & 1) * 64;
    f32x4 acc[4][4] = {};
    const size_t arow0 = (size_t)bm * 128 * K;
    const size_t brow0 = (size_t)bn * 128 * K;

    for (int kt = 0; kt < K; kt += 32) {
#pragma unroll
        for (int i = 0; i < 2; ++i) {
            int base = i * 2048 + wave * 512;
            int flat = base + lane * 8;
            int r = flat >> 5, c = flat & 31;
            gll16(A + arow0 + (size_t)r * K + kt + c, &As[base]);
            gll16(Bw + brow0 + (size_t)r * K + kt + c, &Bs[base]);
        }
        __syncthreads();
        bf16x8 af[4], bfr[4];
#pragma unroll
        for (int mi = 0; mi < 4; ++mi)
            af[mi] = *(const bf16x8_a*)&As[(wr + mi * 16 + l15) * 32 + lhi * 8];
#pragma unroll
        for (int ni = 0; ni < 4; ++ni)
            bfr[ni] = *(const bf16x8_a*)&Bs[(wc + ni * 16 + l15) * 32 + lhi * 8];
#pragma unroll
        for (int mi = 0; mi < 4; ++mi)
#pragma unroll
            for (int ni = 0; ni < 4; ++ni)
                acc[mi][ni] = __builtin_amdgcn_mfma_f32_16x16x32_bf16(
                    af[mi], bfr[ni], acc[mi][ni], 0, 0, 0);
        __syncthreads();
    }
#pragma unroll
    for (int mi = 0; mi < 4; ++mi)
#pragma unroll
        for (int ni = 0; ni < 4; ++ni)
#pragma unroll
            for (int j = 0; j < 4; ++j) {
                int row = bm * 128 + wr + mi * 16 + lhi * 4 + j;
                int col = bn * 128 + wc + ni * 16 + l15;
                float v = acc[mi][ni][j] + bias[col];
                if (OUTF32)
                    ((float*)Cout)[(size_t)row * N + col] = v;
                else
                    ((bf16*)Cout)[(size_t)row * N + col] = (bf16)v;
            }
}

// ---------------- V transpose: Vp[b*2048+s][g*64+d] -> VT[b][g][d][s] ----------------
__global__ __launch_bounds__(256) void vtrans(const bf16* __restrict__ V,
                                              bf16* __restrict__ VT) {
    __shared__ bf16 t[64][65];
    const int s0 = blockIdx.x * 64;
    const int bg = blockIdx.y;
    const int b = bg >> 2, g = bg & 3;
#pragma unroll
    for (int i = 0; i < 16; ++i) {
        int flat = threadIdx.x + i * 256;
        int r = flat >> 6, c = flat & 63;
        t[c][r] = V[(size_t)(b * S_LEN + s0 + r) * KVD + g * DKH + c];
    }
    __syncthreads();
#pragma unroll
    for (int i = 0; i < 16; ++i) {
        int flat = threadIdx.x + i * 256;
        int d = flat >> 6, si = flat & 63;
        VT[((size_t)bg * DKH + d) * S_LEN + s0 + si] = t[d][si];
    }
}

// ---------------- attn ctx: single pass, unnormalized P, normalize at end ----------------
// grid 512 (XCD-swizzled); block 512 = 8 waves x 16 q-rows.
// Writes ctx (bf16) + rinv per q-row. NO prob stores -> load-only pipeline.
__global__ __launch_bounds__(512, 4) void attn_ctx(const bf16* __restrict__ Qp,
                                                   const bf16* __restrict__ Kp,
                                                   const bf16* __restrict__ VT,
                                                   float* __restrict__ rinvArr,
                                                   bf16* __restrict__ ctx) {
    __shared__ bf16 Ks[4][4096];
    __shared__ bf16 Vs[4][4096];
    __shared__ bf16 Ps[8][1024];
    const int raw = blockIdx.x;
    const int wg = (raw & 7) * 64 + (raw >> 3);  // 512 % 8 == 0: bijective
    const int bh = wg >> 4;
    const int qt = wg & 15;
    const int h = bh & (NH - 1), b = bh >> 4, g = h >> 2;
    const int wave = threadIdx.x >> 6, lane = threadIdx.x & 63;
    const int l15 = lane & 15, lhi = lane >> 4;
    const int qrow0 = qt * 128 + wave * 16;

    const bf16* qbase = Qp + (size_t)(b * S_LEN + qrow0 + l15) * DMODEL + h * DKH + lhi * 8;
    bf16x8 aq0 = *(const bf16x8_a*)qbase;
    bf16x8 aq1 = *(const bf16x8_a*)(qbase + 32);

    const int srow = wave * 8 + (lane >> 3);
    const int scc = (lane & 7) ^ ((lane >> 3) & 7);
    const bf16* ksrc = Kp + (size_t)(b * S_LEN + srow) * KVD + g * DKH + scc * 8;
    const bf16* vsrc = VT + ((size_t)(b * NKVH + g) * DKH + srow) * S_LEN + scc * 8;
    const int sw = (l15 & 7) << 4;

    gll16(ksrc, &Ks[0][wave * 512]);
    gll16(vsrc, &Vs[0][wave * 512]);
    gll16(ksrc + (size_t)64 * KVD, &Ks[1][wave * 512]);
    gll16(vsrc + 64, &Vs[1][wave * 512]);
    VWAIT(2);
    __builtin_amdgcn_s_barrier();

    float lsum = 0.f;
    f32x4 cacc[4] = {};
    char* pl = (char*)&Ps[wave][0];

    for (int kt = 0; kt < 32; ++kt) {
        if (kt < 30) {
            gll16(ksrc + (size_t)((kt + 2) * 64) * KVD, &Ks[(kt + 2) & 3][wave * 512]);
            gll16(vsrc + (kt + 2) * 64, &Vs[(kt + 2) & 3][wave * 512]);
        }
        const char* kc = (const char*)&Ks[kt & 3][0];
        f32x4 s[4];
        __builtin_amdgcn_s_setprio(1);
#pragma unroll
        for (int nt = 0; nt < 4; ++nt) {
            int rb = (nt * 16 + l15) * 128;
            bf16x8 k0 = *(const bf16x8_a*)(kc + rb + ((lhi * 16) ^ sw));
            bf16x8 k1 = *(const bf16x8_a*)(kc + rb + ((lhi * 16 + 64) ^ sw));
            f32x4 a = {0.f, 0.f, 0.f, 0.f};
            a = __builtin_amdgcn_mfma_f32_16x16x32_bf16(k0, aq0, a, 0, 0, 0);
            a = __builtin_amdgcn_mfma_f32_16x16x32_bf16(k1, aq1, a, 0, 0, 0);
            s[nt] = a;
        }
        __builtin_amdgcn_s_setprio(0);
        // unnormalized probs -> LDS (bf16); accumulate denominator
#pragma unroll
        for (int nt = 0; nt < 4; ++nt) {
            bf16x4 pb;
#pragma unroll
            for (int j = 0; j < 4; ++j) {
                float p = __builtin_exp2f(s[nt][j] * SCALE_LOG2E);
                lsum += p;
                pb[j] = (bf16)p;
            }
            *(bf16x4_a*)(pl + ((l15 * 128 + nt * 32 + lhi * 8) ^ sw)) = pb;
        }
        bf16x8 ap0 = *(const bf16x8_a*)(pl + ((l15 * 128 + lhi * 16) ^ sw));
        bf16x8 ap1 = *(const bf16x8_a*)(pl + ((l15 * 128 + 64 + lhi * 16) ^ sw));
        const char* vc = (const char*)&Vs[kt & 3][0];
        __builtin_amdgcn_s_setprio(1);
#pragma unroll
        for (int nt = 0; nt < 4; ++nt) {
            int rb = (nt * 16 + l15) * 128;
            bf16x8 v0 = *(const bf16x8_a*)(vc + rb + ((lhi * 16) ^ sw));
            bf16x8 v1 = *(const bf16x8_a*)(vc + rb + ((lhi * 16 + 64) ^ sw));
            cacc[nt] = __builtin_amdgcn_mfma_f32_16x16x32_bf16(ap0, v0, cacc[nt], 0, 0, 0);
            cacc[nt] = __builtin_amdgcn_mfma_f32_16x16x32_bf16(ap1, v1, cacc[nt], 0, 0, 0);
        }
        __builtin_amdgcn_s_setprio(0);
        if (kt < 31) {
            if (kt < 30) { VWAIT(2); } else { VWAIT(0); }
            __builtin_amdgcn_s_barrier();
        }
    }
    // denominator: reduce over lhi groups (lanes {q, q+16, q+32, q+48})
    lsum += __shfl_xor(lsum, 16, 64);
    lsum += __shfl_xor(lsum, 32, 64);
    const float rt = 1.0f / lsum;  // valid in every lane for q = l15
    if (lane < 16) rinvArr[(size_t)bh * S_LEN + qrow0 + lane] = rt;
    float rv[4];
#pragma unroll
    for (int j = 0; j < 4; ++j) rv[j] = __shfl(rt, lhi * 4 + j, 64);
#pragma unroll
    for (int nt = 0; nt < 4; ++nt)
#pragma unroll
        for (int j = 0; j < 4; ++j) {
            int row = qrow0 + lhi * 4 + j;
            ctx[(size_t)(b * S_LEN + row) * DMODEL + h * DKH + nt * 16 + l15] =
                (bf16)(cacc[nt][j] * rv[j]);
        }
}

// ---------------- attn probs: pure streaming writer ----------------
// grid 8192 (XCD-swizzled): bh(32) x qt(32: 64 q-rows) x kg(8: 256 keys).
// K tile (256x64) staged once in LDS; then barrier-free MFMA+exp+store stream.
__global__ __launch_bounds__(256, 4) void attn_probs(const bf16* __restrict__ Qp,
                                                     const bf16* __restrict__ Kp,
                                                     const float* __restrict__ rinvArr,
                                                     float* __restrict__ attn_out) {
    __shared__ bf16 Ks[16384];  // 256 keys x 64 dk, XOR-swizzled rows
    const int raw = blockIdx.x;
    const int wg = (raw & 7) * 1024 + (raw >> 3);  // 8192 % 8 == 0: bijective
    const int bh = wg >> 8;
    const int rem = wg & 255;
    const int qt = rem >> 3;
    const int kg = rem & 7;
    const int h = bh & (NH - 1), b = bh >> 4, g = h >> 2;
    const int tid = threadIdx.x, wave = tid >> 6, lane = tid & 63;
    const int l15 = lane & 15, lhi = lane >> 4;
    const int qrow0 = qt * 64 + wave * 16;

    // stage K: 8 rounds x 4 KB; source column pre-swizzled, LDS linear
    {
        const bf16* ks0 = Kp + (size_t)(b * S_LEN + kg * 256 + wave * 8 + (lane >> 3)) * KVD +
                          g * DKH + ((lane & 7) ^ ((lane >> 3) & 7)) * 8;
#pragma unroll
        for (int i = 0; i < 8; ++i)
            gll16(ks0 + (size_t)(i * 32) * KVD, &Ks[(i * 256 + wave * 64) * 8]);
    }

    const bf16* qbase = Qp + (size_t)(b * S_LEN + qrow0 + l15) * DMODEL + h * DKH + lhi * 8;
    bf16x8 aq0 = *(const bf16x8_a*)qbase;
    bf16x8 aq1 = *(const bf16x8_a*)(qbase + 32);
    const float rinv = rinvArr[(size_t)bh * S_LEN + qrow0 + l15];
    float* arow = attn_out + ((size_t)bh * S_LEN + qrow0 + l15) * S_LEN + kg * 256;
    const int sw = (l15 & 7) << 4;

    VWAIT(0);
    __builtin_amdgcn_s_barrier();

#pragma unroll
    for (int kt2 = 0; kt2 < 4; ++kt2) {
        const char* kc = (const char*)&Ks[0] + kt2 * 64 * 128;
        f32x4 s[4];
        __builtin_amdgcn_s_setprio(1);
#pragma unroll
        for (int nt = 0; nt < 4; ++nt) {
            int rb = (nt * 16 + l15) * 128;
            bf16x8 k0 = *(const bf16x8_a*)(kc + rb + ((lhi * 16) ^ sw));
            bf16x8 k1 = *(const bf16x8_a*)(kc + rb + ((lhi * 16 + 64) ^ sw));
            f32x4 a = {0.f, 0.f, 0.f, 0.f};
            a = __builtin_amdgcn_mfma_f32_16x16x32_bf16(k0, aq0, a, 0, 0, 0);
            a = __builtin_amdgcn_mfma_f32_16x16x32_bf16(k1, aq1, a, 0, 0, 0);
            s[nt] = a;
        }
        __builtin_amdgcn_s_setprio(0);
#pragma unroll
        for (int nt = 0; nt < 4; ++nt) {
            f32x4 p4;
#pragma unroll
            for (int j = 0; j < 4; ++j)
                p4[j] = __builtin_exp2f(s[nt][j] * SCALE_LOG2E) * rinv;
            __builtin_nontemporal_store(p4,
                                        (f32x4g*)(arow + kt2 * 64 + nt * 16 + lhi * 4));
        }
    }
}

extern "C" void kernel_launch(void* const* d_in, const int* in_sizes, int n_in,
                              void* d_out, int out_size, void* d_ws, size_t ws_size,
                              hipStream_t stream) {
    const float* query = (const float*)d_in[0];
    const float* key_i = (const float*)d_in[1];
    const float* value = (const float*)d_in[2];
    const float* Wq = (const float*)d_in[3];
    const float* bq = (const float*)d_in[4];
    const float* Wk = (const float*)d_in[5];
    const float* bk = (const float*)d_in[6];
    const float* Wv = (const float*)d_in[7];
    const float* bv = (const float*)d_in[8];
    const float* Wo = (const float*)d_in[9];
    const float* bo = (const float*)d_in[10];

    char* ws = (char*)d_ws;
    bf16* qx = (bf16*)(ws + 0);
    bf16* kx = (bf16*)(ws + ((size_t)8 << 20));
    bf16* vx = (bf16*)(ws + ((size_t)16 << 20));
    bf16* wqx = (bf16*)(ws + ((size_t)32 << 20));
    bf16* wkx = (bf16*)(ws + ((size_t)34 << 20));
    bf16* wvx = (bf16*)(ws + ((size_t)34 << 20) + ((size_t)512 << 10));
    bf16* wox = (bf16*)(ws + ((size_t)35 << 20));
    bf16* Qp = (bf16*)(ws + ((size_t)37 << 20));
    bf16* Kp = (bf16*)(ws + ((size_t)45 << 20));
    bf16* Vp = (bf16*)(ws + ((size_t)47 << 20));
    bf16* VT = (bf16*)(ws + ((size_t)49 << 20));
    bf16* ctxb = (bf16*)(ws + ((size_t)51 << 20));
    float* rinvArr = (float*)(ws + ((size_t)60 << 20));  // 256 KB

    const int BS = 2 * S_LEN;  // 4096 rows

    cast3_bf16<<<dim3(1024, 3), 256, 0, stream>>>(query, key_i, value, qx, kx, vx,
                                                  BS * DMODEL / 4);
    cast2_bf16<<<dim3(1024, 2), 256, 0, stream>>>(Wq, Wo, wqx, wox, DMODEL * DMODEL / 4);
    cast2_bf16<<<dim3(256, 2), 256, 0, stream>>>(Wk, Wv, wkx, wvx, KVD * DMODEL / 4);

    gemm_bt<0><<<dim3(32, 8), 256, 0, stream>>>(qx, wqx, bq, Qp, BS, DMODEL, DMODEL);
    gemm_bt<0><<<dim3(32, 2), 256, 0, stream>>>(kx, wkx, bk, Kp, BS, KVD, DMODEL);
    gemm_bt<0><<<dim3(32, 2), 256, 0, stream>>>(vx, wvx, bv, Vp, BS, KVD, DMODEL);

    vtrans<<<dim3(32, 8), 256, 0, stream>>>(Vp, VT);

    float* attn_out = (float*)d_out + (size_t)BS * DMODEL;
    attn_ctx<<<512, 512, 0, stream>>>(Qp, Kp, VT, rinvArr, ctxb);
    attn_probs<<<8192, 256, 0, stream>>>(Qp, Kp, rinvArr, attn_out);

    gemm_bt<1><<<dim3(32, 8), 256, 0, stream>>>(ctxb, wox, bo, (float*)d_out, BS, DMODEL, DMODEL);
}

// Round 7
// 308.257 us; speedup vs baseline: 1.7964x; 1.1302x over previous
//
#include <hip/hip_runtime.h>

#define S_LEN 2048
#define DMODEL 1024
#define NH 16
#define NKVH 4
#define DKH 64
#define KVD 256
#define SCALE_LOG2E 0.18033688f  // (1/sqrt(64)) * log2(e)

typedef __bf16 bf16;
typedef bf16  bf16x8 __attribute__((ext_vector_type(8)));
typedef bf16  bf16x4 __attribute__((ext_vector_type(4)));
typedef float f32x4  __attribute__((ext_vector_type(4)));
typedef bf16x8 bf16x8_a __attribute__((may_alias));
typedef bf16x4 bf16x4_a __attribute__((may_alias));
typedef float f32x4g __attribute__((ext_vector_type(4), may_alias));

#define VWAIT(N)                                             \
    do {                                                     \
        asm volatile("s_waitcnt vmcnt(" #N ")" ::: "memory");\
        __builtin_amdgcn_sched_barrier(0);                   \
    } while (0)

// drain LDS ops then barrier: required for CROSS-WAVE LDS handoff with raw barriers
#define LGKM0_BARRIER()                                       \
    do {                                                      \
        asm volatile("s_waitcnt lgkmcnt(0)" ::: "memory");    \
        __builtin_amdgcn_sched_barrier(0);                    \
        __builtin_amdgcn_s_barrier();                         \
        __builtin_amdgcn_sched_barrier(0);                    \
    } while (0)

__device__ __forceinline__ void gll16(const bf16* g, bf16* l) {
    __builtin_amdgcn_global_load_lds(
        (const __attribute__((address_space(1))) void*)g,
        (__attribute__((address_space(3))) void*)l, 16, 0, 0);
}

// ---------------- fused fp32 -> bf16 casts ----------------
__global__ __launch_bounds__(256) void cast3_bf16(const float* __restrict__ a,
                                                  const float* __restrict__ b,
                                                  const float* __restrict__ c,
                                                  bf16* __restrict__ oa, bf16* __restrict__ ob,
                                                  bf16* __restrict__ oc, int n4) {
    const float* src = blockIdx.y == 0 ? a : blockIdx.y == 1 ? b : c;
    bf16* dst = blockIdx.y == 0 ? oa : blockIdx.y == 1 ? ob : oc;
    int stride = gridDim.x * blockDim.x;
    for (int i = blockIdx.x * blockDim.x + threadIdx.x; i < n4; i += stride) {
        f32x4g v = ((const f32x4g*)src)[i];
        bf16x4 o;
        o[0] = (bf16)v[0]; o[1] = (bf16)v[1]; o[2] = (bf16)v[2]; o[3] = (bf16)v[3];
        ((bf16x4*)dst)[i] = o;
    }
}

__global__ __launch_bounds__(256) void cast2_bf16(const float* __restrict__ a,
                                                  const float* __restrict__ b,
                                                  bf16* __restrict__ oa, bf16* __restrict__ ob,
                                                  int n4) {
    const float* src = blockIdx.y == 0 ? a : b;
    bf16* dst = blockIdx.y == 0 ? oa : ob;
    int stride = gridDim.x * blockDim.x;
    for (int i = blockIdx.x * blockDim.x + threadIdx.x; i < n4; i += stride) {
        f32x4g v = ((const f32x4g*)src)[i];
        bf16x4 o;
        o[0] = (bf16)v[0]; o[1] = (bf16)v[1]; o[2] = (bf16)v[2]; o[3] = (bf16)v[3];
        ((bf16x4*)dst)[i] = o;
    }
}

// ---------------- NT GEMM: C[m][n] = sum_k A[m][k]*Bw[n][k] + bias[n] ----------------
template <int OUTF32>
__global__ __launch_bounds__(256) void gemm_bt(const bf16* __restrict__ A,
                                               const bf16* __restrict__ Bw,
                                               const float* __restrict__ bias,
                                               void* __restrict__ Cout,
                                               int M, int N, int K) {
    __shared__ bf16 As[4096];  // 128 x 32
    __shared__ bf16 Bs[4096];
    const int bm = blockIdx.x, bn = blockIdx.y;
    const int tid = threadIdx.x, wave = tid >> 6, lane = tid & 63;
    const int l15 = lane & 15, lhi = lane >> 4;
    const int wr = (wave >> 1) * 64, wc = (wave & 1) * 64;
    f32x4 acc[4][4] = {};
    const size_t arow0 = (size_t)bm * 128 * K;
    const size_t brow0 = (size_t)bn * 128 * K;

    for (int kt = 0; kt < K; kt += 32) {
#pragma unroll
        for (int i = 0; i < 2; ++i) {
            int base = i * 2048 + wave * 512;
            int flat = base + lane * 8;
            int r = flat >> 5, c = flat & 31;
            gll16(A + arow0 + (size_t)r * K + kt + c, &As[base]);
            gll16(Bw + brow0 + (size_t)r * K + kt + c, &Bs[base]);
        }
        __syncthreads();
        bf16x8 af[4], bfr[4];
#pragma unroll
        for (int mi = 0; mi < 4; ++mi)
            af[mi] = *(const bf16x8_a*)&As[(wr + mi * 16 + l15) * 32 + lhi * 8];
#pragma unroll
        for (int ni = 0; ni < 4; ++ni)
            bfr[ni] = *(const bf16x8_a*)&Bs[(wc + ni * 16 + l15) * 32 + lhi * 8];
#pragma unroll
        for (int mi = 0; mi < 4; ++mi)
#pragma unroll
            for (int ni = 0; ni < 4; ++ni)
                acc[mi][ni] = __builtin_amdgcn_mfma_f32_16x16x32_bf16(
                    af[mi], bfr[ni], acc[mi][ni], 0, 0, 0);
        __syncthreads();
    }
#pragma unroll
    for (int mi = 0; mi < 4; ++mi)
#pragma unroll
        for (int ni = 0; ni < 4; ++ni)
#pragma unroll
            for (int j = 0; j < 4; ++j) {
                int row = bm * 128 + wr + mi * 16 + lhi * 4 + j;
                int col = bn * 128 + wc + ni * 16 + l15;
                float v = acc[mi][ni][j] + bias[col];
                if (OUTF32)
                    ((float*)Cout)[(size_t)row * N + col] = v;
                else
                    ((bf16*)Cout)[(size_t)row * N + col] = (bf16)v;
            }
}

// ---------------- V transpose: Vp[b*2048+s][g*64+d] -> VT[b][g][d][s] ----------------
__global__ __launch_bounds__(256) void vtrans(const bf16* __restrict__ V,
                                              bf16* __restrict__ VT) {
    __shared__ bf16 t[64][65];
    const int s0 = blockIdx.x * 64;
    const int bg = blockIdx.y;
    const int b = bg >> 2, g = bg & 3;
#pragma unroll
    for (int i = 0; i < 16; ++i) {
        int flat = threadIdx.x + i * 256;
        int r = flat >> 6, c = flat & 63;
        t[c][r] = V[(size_t)(b * S_LEN + s0 + r) * KVD + g * DKH + c];
    }
    __syncthreads();
#pragma unroll
    for (int i = 0; i < 16; ++i) {
        int flat = threadIdx.x + i * 256;
        int d = flat >> 6, si = flat & 63;
        VT[((size_t)bg * DKH + d) * S_LEN + s0 + si] = t[d][si];
    }
}

// ---------------- attn ctx: single pass, unnormalized P, normalize at end ----------------
__global__ __launch_bounds__(512, 4) void attn_ctx(const bf16* __restrict__ Qp,
                                                   const bf16* __restrict__ Kp,
                                                   const bf16* __restrict__ VT,
                                                   float* __restrict__ rinvArr,
                                                   bf16* __restrict__ ctx) {
    __shared__ bf16 Ks[4][4096];
    __shared__ bf16 Vs[4][4096];
    __shared__ bf16 Ps[8][1024];
    const int raw = blockIdx.x;
    const int wg = (raw & 7) * 64 + (raw >> 3);  // 512 % 8 == 0: bijective
    const int bh = wg >> 4;
    const int qt = wg & 15;
    const int h = bh & (NH - 1), b = bh >> 4, g = h >> 2;
    const int wave = threadIdx.x >> 6, lane = threadIdx.x & 63;
    const int l15 = lane & 15, lhi = lane >> 4;
    const int qrow0 = qt * 128 + wave * 16;

    const bf16* qbase = Qp + (size_t)(b * S_LEN + qrow0 + l15) * DMODEL + h * DKH + lhi * 8;
    bf16x8 aq0 = *(const bf16x8_a*)qbase;
    bf16x8 aq1 = *(const bf16x8_a*)(qbase + 32);

    const int srow = wave * 8 + (lane >> 3);
    const int scc = (lane & 7) ^ ((lane >> 3) & 7);
    const bf16* ksrc = Kp + (size_t)(b * S_LEN + srow) * KVD + g * DKH + scc * 8;
    const bf16* vsrc = VT + ((size_t)(b * NKVH + g) * DKH + srow) * S_LEN + scc * 8;
    const int sw = (l15 & 7) << 4;

    gll16(ksrc, &Ks[0][wave * 512]);
    gll16(vsrc, &Vs[0][wave * 512]);
    gll16(ksrc + (size_t)64 * KVD, &Ks[1][wave * 512]);
    gll16(vsrc + 64, &Vs[1][wave * 512]);
    VWAIT(2);
    __builtin_amdgcn_s_barrier();

    float lsum = 0.f;
    f32x4 cacc[4] = {};
    char* pl = (char*)&Ps[wave][0];

    for (int kt = 0; kt < 32; ++kt) {
        if (kt < 30) {
            gll16(ksrc + (size_t)((kt + 2) * 64) * KVD, &Ks[(kt + 2) & 3][wave * 512]);
            gll16(vsrc + (kt + 2) * 64, &Vs[(kt + 2) & 3][wave * 512]);
        }
        const char* kc = (const char*)&Ks[kt & 3][0];
        f32x4 s[4];
        __builtin_amdgcn_s_setprio(1);
#pragma unroll
        for (int nt = 0; nt < 4; ++nt) {
            int rb = (nt * 16 + l15) * 128;
            bf16x8 k0 = *(const bf16x8_a*)(kc + rb + ((lhi * 16) ^ sw));
            bf16x8 k1 = *(const bf16x8_a*)(kc + rb + ((lhi * 16 + 64) ^ sw));
            f32x4 a = {0.f, 0.f, 0.f, 0.f};
            a = __builtin_amdgcn_mfma_f32_16x16x32_bf16(k0, aq0, a, 0, 0, 0);
            a = __builtin_amdgcn_mfma_f32_16x16x32_bf16(k1, aq1, a, 0, 0, 0);
            s[nt] = a;
        }
        __builtin_amdgcn_s_setprio(0);
#pragma unroll
        for (int nt = 0; nt < 4; ++nt) {
            bf16x4 pb;
#pragma unroll
            for (int j = 0; j < 4; ++j) {
                float p = __builtin_exp2f(s[nt][j] * SCALE_LOG2E);
                lsum += p;
                pb[j] = (bf16)p;
            }
            *(bf16x4_a*)(pl + ((l15 * 128 + nt * 32 + lhi * 8) ^ sw)) = pb;
        }
        bf16x8 ap0 = *(const bf16x8_a*)(pl + ((l15 * 128 + lhi * 16) ^ sw));
        bf16x8 ap1 = *(const bf16x8_a*)(pl + ((l15 * 128 + 64 + lhi * 16) ^ sw));
        const char* vc = (const char*)&Vs[kt & 3][0];
        __builtin_amdgcn_s_setprio(1);
#pragma unroll
        for (int nt = 0; nt < 4; ++nt) {
            int rb = (nt * 16 + l15) * 128;
            bf16x8 v0 = *(const bf16x8_a*)(vc + rb + ((lhi * 16) ^ sw));
            bf16x8 v1 = *(const bf16x8_a*)(vc + rb + ((lhi * 16 + 64) ^ sw));
            cacc[nt] = __builtin_amdgcn_mfma_f32_16x16x32_bf16(ap0, v0, cacc[nt], 0, 0, 0);
            cacc[nt] = __builtin_amdgcn_mfma_f32_16x16x32_bf16(ap1, v1, cacc[nt], 0, 0, 0);
        }
        __builtin_amdgcn_s_setprio(0);
        if (kt < 31) {
            if (kt < 30) { VWAIT(2); } else { VWAIT(0); }
            __builtin_amdgcn_s_barrier();
        }
    }
    lsum += __shfl_xor(lsum, 16, 64);
    lsum += __shfl_xor(lsum, 32, 64);
    const float rt = 1.0f / lsum;
    if (lane < 16) rinvArr[(size_t)bh * S_LEN + qrow0 + lane] = rt;
    float rv[4];
#pragma unroll
    for (int j = 0; j < 4; ++j) rv[j] = __shfl(rt, lhi * 4 + j, 64);
#pragma unroll
    for (int nt = 0; nt < 4; ++nt)
#pragma unroll
        for (int j = 0; j < 4; ++j) {
            int row = qrow0 + lhi * 4 + j;
            ctx[(size_t)(b * S_LEN + row) * DMODEL + h * DKH + nt * 16 + l15] =
                (bf16)(cacc[nt][j] * rv[j]);
        }
}

// ---------------- attn probs: streaming writer with COALESCED 1KB stores ----------------
// grid 4096 (XCD-swizzled): bh(32) x qt(128: 16 q-rows). Block 256 = 4 waves.
// 8 chunks of 256 keys: stage K (dbuf, counted vmcnt) -> MFMA (wave = 64-key band)
// -> P transpose via 16x256 fp32 swizzled LDS (CROSS-WAVE: lgkm-drained barrier)
// -> 1KB-contiguous dwordx4 row stores.
__global__ __launch_bounds__(256, 2) void attn_probs(const bf16* __restrict__ Qp,
                                                     const bf16* __restrict__ Kp,
                                                     const float* __restrict__ rinvArr,
                                                     float* __restrict__ attn_out) {
    __shared__ bf16 Ks[2][16384];  // 2 x [256 keys][64 dk], XOR-swizzled rows
    __shared__ float Pf[4096];     // [16 q][256 k], XOR-swizzled
    const int raw = blockIdx.x;
    const int wg = (raw & 7) * 512 + (raw >> 3);  // 4096 % 8 == 0: bijective
    const int bh = wg >> 7;
    const int qt = wg & 127;
    const int h = bh & (NH - 1), b = bh >> 4, g = h >> 2;
    const int wave = threadIdx.x >> 6, lane = threadIdx.x & 63;
    const int l15 = lane & 15, lhi = lane >> 4;
    const int qrow0 = qt * 16;

    const bf16* qbase = Qp + (size_t)(b * S_LEN + qrow0 + l15) * DMODEL + h * DKH + lhi * 8;
    bf16x8 aq0 = *(const bf16x8_a*)qbase;
    bf16x8 aq1 = *(const bf16x8_a*)(qbase + 32);
    const float rinv = rinvArr[(size_t)bh * S_LEN + qrow0 + l15];

    // staging: wave stages its own 64-key band; source column pre-swizzled
    const int skey = wave * 64 + (lane >> 3);
    const int scol = ((lane & 7) ^ ((lane >> 3) & 7)) * 8;
    const bf16* ksrc = Kp + (size_t)(b * S_LEN + skey) * KVD + g * DKH + scol;
    const int sw = (l15 & 7) << 4;
    float* arow_base = attn_out + ((size_t)bh * S_LEN + qrow0) * S_LEN;
    char* pfb = (char*)&Pf[0];

    // prologue: stage chunk 0
#pragma unroll
    for (int i = 0; i < 8; ++i)
        gll16(ksrc + (size_t)(i * 8) * KVD, &Ks[0][wave * 4096 + i * 512]);

    for (int c = 0; c < 8; ++c) {
        if (c < 7) {
#pragma unroll
            for (int i = 0; i < 8; ++i)
                gll16(ksrc + (size_t)((c + 1) * 256 + i * 8) * KVD,
                      &Ks[(c + 1) & 1][wave * 4096 + i * 512]);
        }
        // wait own K(c); leave next-chunk loads + last-chunk stores in flight
        if (c == 0) { VWAIT(8); }
        else if (c == 7) { VWAIT(4); }
        else { VWAIT(12); }
        __builtin_amdgcn_s_barrier();  // K(c) ready for all waves

        const char* kc = (const char*)&Ks[c & 1][wave * 4096];
        f32x4 s[4];
        __builtin_amdgcn_s_setprio(1);
#pragma unroll
        for (int nt = 0; nt < 4; ++nt) {
            int rb = (nt * 16 + l15) * 128;
            bf16x8 k0 = *(const bf16x8_a*)(kc + rb + ((lhi * 16) ^ sw));
            bf16x8 k1 = *(const bf16x8_a*)(kc + rb + ((lhi * 16 + 64) ^ sw));
            f32x4 a = {0.f, 0.f, 0.f, 0.f};
            a = __builtin_amdgcn_mfma_f32_16x16x32_bf16(k0, aq0, a, 0, 0, 0);
            a = __builtin_amdgcn_mfma_f32_16x16x32_bf16(k1, aq1, a, 0, 0, 0);
            s[nt] = a;
        }
        __builtin_amdgcn_s_setprio(0);
        // P -> LDS fp32, swizzled: row = q (l15), col = wave*64 + nt*16 + lhi*4
#pragma unroll
        for (int nt = 0; nt < 4; ++nt) {
            f32x4 p4;
#pragma unroll
            for (int j = 0; j < 4; ++j)
                p4[j] = __builtin_exp2f(s[nt][j] * SCALE_LOG2E) * rinv;
            *(f32x4g*)(pfb + ((l15 * 1024 + wave * 256 + nt * 64 + lhi * 16) ^ sw)) = p4;
        }
        // CROSS-WAVE handoff: drain ds_writes before the barrier (R6 bug fix)
        LGKM0_BARRIER();
        // coalesced stores: wave handles rows wave*4 .. +3; 1KB contiguous per instr
#pragma unroll
        for (int r = 0; r < 4; ++r) {
            int row = wave * 4 + r;
            f32x4 v = *(const f32x4g*)(pfb + ((row * 1024 + lane * 16) ^ ((row & 7) << 4)));
            *(f32x4g*)(arow_base + (size_t)row * S_LEN + c * 256 + lane * 4) = v;
        }
    }
}

extern "C" void kernel_launch(void* const* d_in, const int* in_sizes, int n_in,
                              void* d_out, int out_size, void* d_ws, size_t ws_size,
                              hipStream_t stream) {
    const float* query = (const float*)d_in[0];
    const float* key_i = (const float*)d_in[1];
    const float* value = (const float*)d_in[2];
    const float* Wq = (const float*)d_in[3];
    const float* bq = (const float*)d_in[4];
    const float* Wk = (const float*)d_in[5];
    const float* bk = (const float*)d_in[6];
    const float* Wv = (const float*)d_in[7];
    const float* bv = (const float*)d_in[8];
    const float* Wo = (const float*)d_in[9];
    const float* bo = (const float*)d_in[10];

    char* ws = (char*)d_ws;
    bf16* qx = (bf16*)(ws + 0);
    bf16* kx = (bf16*)(ws + ((size_t)8 << 20));
    bf16* vx = (bf16*)(ws + ((size_t)16 << 20));
    bf16* wqx = (bf16*)(ws + ((size_t)32 << 20));
    bf16* wkx = (bf16*)(ws + ((size_t)34 << 20));
    bf16* wvx = (bf16*)(ws + ((size_t)34 << 20) + ((size_t)512 << 10));
    bf16* wox = (bf16*)(ws + ((size_t)35 << 20));
    bf16* Qp = (bf16*)(ws + ((size_t)37 << 20));
    bf16* Kp = (bf16*)(ws + ((size_t)45 << 20));
    bf16* Vp = (bf16*)(ws + ((size_t)47 << 20));
    bf16* VT = (bf16*)(ws + ((size_t)49 << 20));
    bf16* ctxb = (bf16*)(ws + ((size_t)51 << 20));
    float* rinvArr = (float*)(ws + ((size_t)60 << 20));  // 256 KB

    const int BS = 2 * S_LEN;  // 4096 rows

    cast3_bf16<<<dim3(1024, 3), 256, 0, stream>>>(query, key_i, value, qx, kx, vx,
                                                  BS * DMODEL / 4);
    cast2_bf16<<<dim3(1024, 2), 256, 0, stream>>>(Wq, Wo, wqx, wox, DMODEL * DMODEL / 4);
    cast2_bf16<<<dim3(256, 2), 256, 0, stream>>>(Wk, Wv, wkx, wvx, KVD * DMODEL / 4);

    gemm_bt<0><<<dim3(32, 8), 256, 0, stream>>>(qx, wqx, bq, Qp, BS, DMODEL, DMODEL);
    gemm_bt<0><<<dim3(32, 2), 256, 0, stream>>>(kx, wkx, bk, Kp, BS, KVD, DMODEL);
    gemm_bt<0><<<dim3(32, 2), 256, 0, stream>>>(vx, wvx, bv, Vp, BS, KVD, DMODEL);

    vtrans<<<dim3(32, 8), 256, 0, stream>>>(Vp, VT);

    float* attn_out = (float*)d_out + (size_t)BS * DMODEL;
    attn_ctx<<<512, 512, 0, stream>>>(Qp, Kp, VT, rinvArr, ctxb);
    attn_probs<<<4096, 256, 0, stream>>>(Qp, Kp, rinvArr, attn_out);

    gemm_bt<1><<<dim3(32, 8), 256, 0, stream>>>(ctxb, wox, bo, (float*)d_out, BS, DMODEL, DMODEL);
}

// Round 8
// 307.845 us; speedup vs baseline: 1.7988x; 1.0013x over previous
//
#include <hip/hip_runtime.h>

#define S_LEN 2048
#define DMODEL 1024
#define NH 16
#define NKVH 4
#define DKH 64
#define KVD 256
#define SCALE_LOG2E 0.18033688f  // (1/sqrt(64)) * log2(e)

typedef __bf16 bf16;
typedef bf16  bf16x8 __attribute__((ext_vector_type(8)));
typedef bf16  bf16x4 __attribute__((ext_vector_type(4)));
typedef float f32x4  __attribute__((ext_vector_type(4)));
typedef bf16x8 bf16x8_a __attribute__((may_alias));
typedef bf16x4 bf16x4_a __attribute__((may_alias));
typedef float f32x4g __attribute__((ext_vector_type(4), may_alias));

#define VWAIT(N)                                             \
    do {                                                     \
        asm volatile("s_waitcnt vmcnt(" #N ")" ::: "memory");\
        __builtin_amdgcn_sched_barrier(0);                   \
    } while (0)

// drain LDS ops then barrier: required for CROSS-WAVE LDS handoff with raw barriers
#define LGKM0_BARRIER()                                       \
    do {                                                      \
        asm volatile("s_waitcnt lgkmcnt(0)" ::: "memory");    \
        __builtin_amdgcn_sched_barrier(0);                    \
        __builtin_amdgcn_s_barrier();                         \
        __builtin_amdgcn_sched_barrier(0);                    \
    } while (0)

__device__ __forceinline__ void gll16(const bf16* g, bf16* l) {
    __builtin_amdgcn_global_load_lds(
        (const __attribute__((address_space(1))) void*)g,
        (__attribute__((address_space(3))) void*)l, 16, 0, 0);
}

// ---------------- fused fp32 -> bf16 casts ----------------
__global__ __launch_bounds__(256) void cast3_bf16(const float* __restrict__ a,
                                                  const float* __restrict__ b,
                                                  const float* __restrict__ c,
                                                  bf16* __restrict__ oa, bf16* __restrict__ ob,
                                                  bf16* __restrict__ oc, int n4) {
    const float* src = blockIdx.y == 0 ? a : blockIdx.y == 1 ? b : c;
    bf16* dst = blockIdx.y == 0 ? oa : blockIdx.y == 1 ? ob : oc;
    int stride = gridDim.x * blockDim.x;
    for (int i = blockIdx.x * blockDim.x + threadIdx.x; i < n4; i += stride) {
        f32x4g v = ((const f32x4g*)src)[i];
        bf16x4 o;
        o[0] = (bf16)v[0]; o[1] = (bf16)v[1]; o[2] = (bf16)v[2]; o[3] = (bf16)v[3];
        ((bf16x4*)dst)[i] = o;
    }
}

__global__ __launch_bounds__(256) void cast2_bf16(const float* __restrict__ a,
                                                  const float* __restrict__ b,
                                                  bf16* __restrict__ oa, bf16* __restrict__ ob,
                                                  int n4) {
    const float* src = blockIdx.y == 0 ? a : b;
    bf16* dst = blockIdx.y == 0 ? oa : ob;
    int stride = gridDim.x * blockDim.x;
    for (int i = blockIdx.x * blockDim.x + threadIdx.x; i < n4; i += stride) {
        f32x4g v = ((const f32x4g*)src)[i];
        bf16x4 o;
        o[0] = (bf16)v[0]; o[1] = (bf16)v[1]; o[2] = (bf16)v[2]; o[3] = (bf16)v[3];
        ((bf16x4*)dst)[i] = o;
    }
}

// ---------------- NT GEMM: C[m][n] = sum_k A[m][k]*Bw[n][k] + bias[n] ----------------
template <int OUTF32>
__global__ __launch_bounds__(256) void gemm_bt(const bf16* __restrict__ A,
                                               const bf16* __restrict__ Bw,
                                               const float* __restrict__ bias,
                                               void* __restrict__ Cout,
                                               int M, int N, int K) {
    __shared__ bf16 As[4096];  // 128 x 32
    __shared__ bf16 Bs[4096];
    const int bm = blockIdx.x, bn = blockIdx.y;
    const int tid = threadIdx.x, wave = tid >> 6, lane = tid & 63;
    const int l15 = lane & 15, lhi = lane >> 4;
    const int wr = (wave >> 1) * 64, wc = (wave & 1) * 64;
    f32x4 acc[4][4] = {};
    const size_t arow0 = (size_t)bm * 128 * K;
    const size_t brow0 = (size_t)bn * 128 * K;

    for (int kt = 0; kt < K; kt += 32) {
#pragma unroll
        for (int i = 0; i < 2; ++i) {
            int base = i * 2048 + wave * 512;
            int flat = base + lane * 8;
            int r = flat >> 5, c = flat & 31;
            gll16(A + arow0 + (size_t)r * K + kt + c, &As[base]);
            gll16(Bw + brow0 + (size_t)r * K + kt + c, &Bs[base]);
        }
        __syncthreads();
        bf16x8 af[4], bfr[4];
#pragma unroll
        for (int mi = 0; mi < 4; ++mi)
            af[mi] = *(const bf16x8_a*)&As[(wr + mi * 16 + l15) * 32 + lhi * 8];
#pragma unroll
        for (int ni = 0; ni < 4; ++ni)
            bfr[ni] = *(const bf16x8_a*)&Bs[(wc + ni * 16 + l15) * 32 + lhi * 8];
#pragma unroll
        for (int mi = 0; mi < 4; ++mi)
#pragma unroll
            for (int ni = 0; ni < 4; ++ni)
                acc[mi][ni] = __builtin_amdgcn_mfma_f32_16x16x32_bf16(
                    af[mi], bfr[ni], acc[mi][ni], 0, 0, 0);
        __syncthreads();
    }
#pragma unroll
    for (int mi = 0; mi < 4; ++mi)
#pragma unroll
        for (int ni = 0; ni < 4; ++ni)
#pragma unroll
            for (int j = 0; j < 4; ++j) {
                int row = bm * 128 + wr + mi * 16 + lhi * 4 + j;
                int col = bn * 128 + wc + ni * 16 + l15;
                float v = acc[mi][ni][j] + bias[col];
                if (OUTF32)
                    ((float*)Cout)[(size_t)row * N + col] = v;
                else
                    ((bf16*)Cout)[(size_t)row * N + col] = (bf16)v;
            }
}

// ---------------- V transpose: Vp[b*2048+s][g*64+d] -> VT[b][g][d][s] ----------------
__global__ __launch_bounds__(256) void vtrans(const bf16* __restrict__ V,
                                              bf16* __restrict__ VT) {
    __shared__ bf16 t[64][65];
    const int s0 = blockIdx.x * 64;
    const int bg = blockIdx.y;
    const int b = bg >> 2, g = bg & 3;
#pragma unroll
    for (int i = 0; i < 16; ++i) {
        int flat = threadIdx.x + i * 256;
        int r = flat >> 6, c = flat & 63;
        t[c][r] = V[(size_t)(b * S_LEN + s0 + r) * KVD + g * DKH + c];
    }
    __syncthreads();
#pragma unroll
    for (int i = 0; i < 16; ++i) {
        int flat = threadIdx.x + i * 256;
        int d = flat >> 6, si = flat & 63;
        VT[((size_t)bg * DKH + d) * S_LEN + s0 + si] = t[d][si];
    }
}

// ---------------- attn ctx: PV lags QK by one K-tile (exp chain off critical path) ----------------
// grid 512 (XCD-swizzled); block 512 = 8 waves x 16 q-rows. Unnormalized P; normalize at end.
__global__ __launch_bounds__(512, 4) void attn_ctx(const bf16* __restrict__ Qp,
                                                   const bf16* __restrict__ Kp,
                                                   const bf16* __restrict__ VT,
                                                   float* __restrict__ rinvArr,
                                                   bf16* __restrict__ ctx) {
    __shared__ bf16 Ks[4][4096];  // 32 KB ring
    __shared__ bf16 Vs[4][4096];  // 32 KB ring
    __shared__ bf16 Ps[8][1024];  // 16 KB, per-wave 16x64 (write->read same wave, in-order DS)
    const int raw = blockIdx.x;
    const int wg = (raw & 7) * 64 + (raw >> 3);  // 512 % 8 == 0: bijective
    const int bh = wg >> 4;
    const int qt = wg & 15;
    const int h = bh & (NH - 1), b = bh >> 4, g = h >> 2;
    const int wave = threadIdx.x >> 6, lane = threadIdx.x & 63;
    const int l15 = lane & 15, lhi = lane >> 4;
    const int qrow0 = qt * 128 + wave * 16;

    const bf16* qbase = Qp + (size_t)(b * S_LEN + qrow0 + l15) * DMODEL + h * DKH + lhi * 8;
    bf16x8 aq0 = *(const bf16x8_a*)qbase;
    bf16x8 aq1 = *(const bf16x8_a*)(qbase + 32);

    const int srow = wave * 8 + (lane >> 3);
    const int scc = (lane & 7) ^ ((lane >> 3) & 7);
    const bf16* ksrc = Kp + (size_t)(b * S_LEN + srow) * KVD + g * DKH + scc * 8;
    const bf16* vsrc = VT + ((size_t)(b * NKVH + g) * DKH + srow) * S_LEN + scc * 8;
    const int sw = (l15 & 7) << 4;

    gll16(ksrc, &Ks[0][wave * 512]);
    gll16(vsrc, &Vs[0][wave * 512]);
    gll16(ksrc + (size_t)64 * KVD, &Ks[1][wave * 512]);
    gll16(vsrc + 64, &Vs[1][wave * 512]);
    VWAIT(2);
    __builtin_amdgcn_s_barrier();

    float lsum = 0.f;
    f32x4 cacc[4] = {};
    char* pl = (char*)&Ps[wave][0];
    bf16x4 pb0, pb1, pb2, pb3;  // P(kt-1) held in registers across the barrier

    // ---- iter kt = 0: QK + exp only (no PV yet) ----
    {
        gll16(ksrc + (size_t)(2 * 64) * KVD, &Ks[2][wave * 512]);
        gll16(vsrc + 2 * 64, &Vs[2][wave * 512]);
        const char* kc = (const char*)&Ks[0][0];
        f32x4 s[4];
        __builtin_amdgcn_s_setprio(1);
#pragma unroll
        for (int nt = 0; nt < 4; ++nt) {
            int rb = (nt * 16 + l15) * 128;
            bf16x8 k0 = *(const bf16x8_a*)(kc + rb + ((lhi * 16) ^ sw));
            bf16x8 k1 = *(const bf16x8_a*)(kc + rb + ((lhi * 16 + 64) ^ sw));
            f32x4 a = {0.f, 0.f, 0.f, 0.f};
            a = __builtin_amdgcn_mfma_f32_16x16x32_bf16(k0, aq0, a, 0, 0, 0);
            a = __builtin_amdgcn_mfma_f32_16x16x32_bf16(k1, aq1, a, 0, 0, 0);
            s[nt] = a;
        }
        __builtin_amdgcn_s_setprio(0);
        bf16x4 pbs[4];
#pragma unroll
        for (int nt = 0; nt < 4; ++nt)
#pragma unroll
            for (int j = 0; j < 4; ++j) {
                float p = __builtin_exp2f(s[nt][j] * SCALE_LOG2E);
                lsum += p;
                pbs[nt][j] = (bf16)p;
            }
        pb0 = pbs[0]; pb1 = pbs[1]; pb2 = pbs[2]; pb3 = pbs[3];
        VWAIT(2);
        __builtin_amdgcn_s_barrier();
    }

    // ---- main loop kt = 1..31: {write P(kt-1), read ap} || QK(kt) -> PV(kt-1) -> exp(kt) ----
    for (int kt = 1; kt < 32; ++kt) {
        if (kt < 30) {
            gll16(ksrc + (size_t)((kt + 2) * 64) * KVD, &Ks[(kt + 2) & 3][wave * 512]);
            gll16(vsrc + (kt + 2) * 64, &Vs[(kt + 2) & 3][wave * 512]);
        }
        // P(kt-1): regs -> LDS -> A-frags (same-wave in-order DS; no barrier needed)
        *(bf16x4_a*)(pl + ((l15 * 128 + 0 * 32 + lhi * 8) ^ sw)) = pb0;
        *(bf16x4_a*)(pl + ((l15 * 128 + 1 * 32 + lhi * 8) ^ sw)) = pb1;
        *(bf16x4_a*)(pl + ((l15 * 128 + 2 * 32 + lhi * 8) ^ sw)) = pb2;
        *(bf16x4_a*)(pl + ((l15 * 128 + 3 * 32 + lhi * 8) ^ sw)) = pb3;
        bf16x8 ap0 = *(const bf16x8_a*)(pl + ((l15 * 128 + lhi * 16) ^ sw));
        bf16x8 ap1 = *(const bf16x8_a*)(pl + ((l15 * 128 + 64 + lhi * 16) ^ sw));

        const char* kc = (const char*)&Ks[kt & 3][0];
        f32x4 s[4];
        __builtin_amdgcn_s_setprio(1);
#pragma unroll
        for (int nt = 0; nt < 4; ++nt) {
            int rb = (nt * 16 + l15) * 128;
            bf16x8 k0 = *(const bf16x8_a*)(kc + rb + ((lhi * 16) ^ sw));
            bf16x8 k1 = *(const bf16x8_a*)(kc + rb + ((lhi * 16 + 64) ^ sw));
            f32x4 a = {0.f, 0.f, 0.f, 0.f};
            a = __builtin_amdgcn_mfma_f32_16x16x32_bf16(k0, aq0, a, 0, 0, 0);
            a = __builtin_amdgcn_mfma_f32_16x16x32_bf16(k1, aq1, a, 0, 0, 0);
            s[nt] = a;
        }
        // PV(kt-1)
        const char* vc = (const char*)&Vs[(kt - 1) & 3][0];
#pragma unroll
        for (int nt = 0; nt < 4; ++nt) {
            int rb = (nt * 16 + l15) * 128;
            bf16x8 v0 = *(const bf16x8_a*)(vc + rb + ((lhi * 16) ^ sw));
            bf16x8 v1 = *(const bf16x8_a*)(vc + rb + ((lhi * 16 + 64) ^ sw));
            cacc[nt] = __builtin_amdgcn_mfma_f32_16x16x32_bf16(ap0, v0, cacc[nt], 0, 0, 0);
            cacc[nt] = __builtin_amdgcn_mfma_f32_16x16x32_bf16(ap1, v1, cacc[nt], 0, 0, 0);
        }
        __builtin_amdgcn_s_setprio(0);
        // exp(kt) -> registers (consumed next iteration)
        bf16x4 pbs[4];
#pragma unroll
        for (int nt = 0; nt < 4; ++nt)
#pragma unroll
            for (int j = 0; j < 4; ++j) {
                float p = __builtin_exp2f(s[nt][j] * SCALE_LOG2E);
                lsum += p;
                pbs[nt][j] = (bf16)p;
            }
        pb0 = pbs[0]; pb1 = pbs[1]; pb2 = pbs[2]; pb3 = pbs[3];
        if (kt < 31) {
            if (kt < 30) { VWAIT(2); } else { VWAIT(0); }
            __builtin_amdgcn_s_barrier();
        }
    }
    // ---- epilogue: PV(31) ----
    {
        *(bf16x4_a*)(pl + ((l15 * 128 + 0 * 32 + lhi * 8) ^ sw)) = pb0;
        *(bf16x4_a*)(pl + ((l15 * 128 + 1 * 32 + lhi * 8) ^ sw)) = pb1;
        *(bf16x4_a*)(pl + ((l15 * 128 + 2 * 32 + lhi * 8) ^ sw)) = pb2;
        *(bf16x4_a*)(pl + ((l15 * 128 + 3 * 32 + lhi * 8) ^ sw)) = pb3;
        bf16x8 ap0 = *(const bf16x8_a*)(pl + ((l15 * 128 + lhi * 16) ^ sw));
        bf16x8 ap1 = *(const bf16x8_a*)(pl + ((l15 * 128 + 64 + lhi * 16) ^ sw));
        const char* vc = (const char*)&Vs[31 & 3][0];
#pragma unroll
        for (int nt = 0; nt < 4; ++nt) {
            int rb = (nt * 16 + l15) * 128;
            bf16x8 v0 = *(const bf16x8_a*)(vc + rb + ((lhi * 16) ^ sw));
            bf16x8 v1 = *(const bf16x8_a*)(vc + rb + ((lhi * 16 + 64) ^ sw));
            cacc[nt] = __builtin_amdgcn_mfma_f32_16x16x32_bf16(ap0, v0, cacc[nt], 0, 0, 0);
            cacc[nt] = __builtin_amdgcn_mfma_f32_16x16x32_bf16(ap1, v1, cacc[nt], 0, 0, 0);
        }
    }
    lsum += __shfl_xor(lsum, 16, 64);
    lsum += __shfl_xor(lsum, 32, 64);
    const float rt = 1.0f / lsum;
    if (lane < 16) rinvArr[(size_t)bh * S_LEN + qrow0 + lane] = rt;
    float rv[4];
#pragma unroll
    for (int j = 0; j < 4; ++j) rv[j] = __shfl(rt, lhi * 4 + j, 64);
#pragma unroll
    for (int nt = 0; nt < 4; ++nt)
#pragma unroll
        for (int j = 0; j < 4; ++j) {
            int row = qrow0 + lhi * 4 + j;
            ctx[(size_t)(b * S_LEN + row) * DMODEL + h * DKH + nt * 16 + l15] =
                (bf16)(cacc[nt][j] * rv[j]);
        }
}

// ---------------- attn probs: streaming writer with COALESCED 1KB stores ----------------
// grid 4096 (XCD-swizzled): bh(32) x qt(128: 16 q-rows). Block 256 = 4 waves.
__global__ __launch_bounds__(256, 2) void attn_probs(const bf16* __restrict__ Qp,
                                                     const bf16* __restrict__ Kp,
                                                     const float* __restrict__ rinvArr,
                                                     float* __restrict__ attn_out) {
    __shared__ bf16 Ks[2][16384];  // 2 x [256 keys][64 dk], XOR-swizzled rows
    __shared__ float Pf[4096];     // [16 q][256 k], XOR-swizzled
    const int raw = blockIdx.x;
    const int wg = (raw & 7) * 512 + (raw >> 3);  // 4096 % 8 == 0: bijective
    const int bh = wg >> 7;
    const int qt = wg & 127;
    const int h = bh & (NH - 1), b = bh >> 4, g = h >> 2;
    const int wave = threadIdx.x >> 6, lane = threadIdx.x & 63;
    const int l15 = lane & 15, lhi = lane >> 4;
    const int qrow0 = qt * 16;

    const bf16* qbase = Qp + (size_t)(b * S_LEN + qrow0 + l15) * DMODEL + h * DKH + lhi * 8;
    bf16x8 aq0 = *(const bf16x8_a*)qbase;
    bf16x8 aq1 = *(const bf16x8_a*)(qbase + 32);
    const float rinv = rinvArr[(size_t)bh * S_LEN + qrow0 + l15];

    const int skey = wave * 64 + (lane >> 3);
    const int scol = ((lane & 7) ^ ((lane >> 3) & 7)) * 8;
    const bf16* ksrc = Kp + (size_t)(b * S_LEN + skey) * KVD + g * DKH + scol;
    const int sw = (l15 & 7) << 4;
    float* arow_base = attn_out + ((size_t)bh * S_LEN + qrow0) * S_LEN;
    char* pfb = (char*)&Pf[0];

#pragma unroll
    for (int i = 0; i < 8; ++i)
        gll16(ksrc + (size_t)(i * 8) * KVD, &Ks[0][wave * 4096 + i * 512]);

    for (int c = 0; c < 8; ++c) {
        if (c < 7) {
#pragma unroll
            for (int i = 0; i < 8; ++i)
                gll16(ksrc + (size_t)((c + 1) * 256 + i * 8) * KVD,
                      &Ks[(c + 1) & 1][wave * 4096 + i * 512]);
        }
        if (c == 0) { VWAIT(8); }
        else if (c == 7) { VWAIT(4); }
        else { VWAIT(12); }
        __builtin_amdgcn_s_barrier();  // K(c) ready for all waves

        const char* kc = (const char*)&Ks[c & 1][wave * 4096];
        f32x4 s[4];
        __builtin_amdgcn_s_setprio(1);
#pragma unroll
        for (int nt = 0; nt < 4; ++nt) {
            int rb = (nt * 16 + l15) * 128;
            bf16x8 k0 = *(const bf16x8_a*)(kc + rb + ((lhi * 16) ^ sw));
            bf16x8 k1 = *(const bf16x8_a*)(kc + rb + ((lhi * 16 + 64) ^ sw));
            f32x4 a = {0.f, 0.f, 0.f, 0.f};
            a = __builtin_amdgcn_mfma_f32_16x16x32_bf16(k0, aq0, a, 0, 0, 0);
            a = __builtin_amdgcn_mfma_f32_16x16x32_bf16(k1, aq1, a, 0, 0, 0);
            s[nt] = a;
        }
        __builtin_amdgcn_s_setprio(0);
#pragma unroll
        for (int nt = 0; nt < 4; ++nt) {
            f32x4 p4;
#pragma unroll
            for (int j = 0; j < 4; ++j)
                p4[j] = __builtin_exp2f(s[nt][j] * SCALE_LOG2E) * rinv;
            *(f32x4g*)(pfb + ((l15 * 1024 + wave * 256 + nt * 64 + lhi * 16) ^ sw)) = p4;
        }
        LGKM0_BARRIER();  // cross-wave P handoff
#pragma unroll
        for (int r = 0; r < 4; ++r) {
            int row = wave * 4 + r;
            f32x4 v = *(const f32x4g*)(pfb + ((row * 1024 + lane * 16) ^ ((row & 7) << 4)));
            *(f32x4g*)(arow_base + (size_t)row * S_LEN + c * 256 + lane * 4) = v;
        }
    }
}

extern "C" void kernel_launch(void* const* d_in, const int* in_sizes, int n_in,
                              void* d_out, int out_size, void* d_ws, size_t ws_size,
                              hipStream_t stream) {
    const float* query = (const float*)d_in[0];
    const float* key_i = (const float*)d_in[1];
    const float* value = (const float*)d_in[2];
    const float* Wq = (const float*)d_in[3];
    const float* bq = (const float*)d_in[4];
    const float* Wk = (const float*)d_in[5];
    const float* bk = (const float*)d_in[6];
    const float* Wv = (const float*)d_in[7];
    const float* bv = (const float*)d_in[8];
    const float* Wo = (const float*)d_in[9];
    const float* bo = (const float*)d_in[10];

    char* ws = (char*)d_ws;
    bf16* qx = (bf16*)(ws + 0);
    bf16* kx = (bf16*)(ws + ((size_t)8 << 20));
    bf16* vx = (bf16*)(ws + ((size_t)16 << 20));
    bf16* wqx = (bf16*)(ws + ((size_t)32 << 20));
    bf16* wkx = (bf16*)(ws + ((size_t)34 << 20));
    bf16* wvx = (bf16*)(ws + ((size_t)34 << 20) + ((size_t)512 << 10));
    bf16* wox = (bf16*)(ws + ((size_t)35 << 20));
    bf16* Qp = (bf16*)(ws + ((size_t)37 << 20));
    bf16* Kp = (bf16*)(ws + ((size_t)45 << 20));
    bf16* Vp = (bf16*)(ws + ((size_t)47 << 20));
    bf16* VT = (bf16*)(ws + ((size_t)49 << 20));
    bf16* ctxb = (bf16*)(ws + ((size_t)51 << 20));
    float* rinvArr = (float*)(ws + ((size_t)60 << 20));  // 256 KB

    const int BS = 2 * S_LEN;  // 4096 rows

    cast3_bf16<<<dim3(1024, 3), 256, 0, stream>>>(query, key_i, value, qx, kx, vx,
                                                  BS * DMODEL / 4);
    cast2_bf16<<<dim3(1024, 2), 256, 0, stream>>>(Wq, Wo, wqx, wox, DMODEL * DMODEL / 4);
    cast2_bf16<<<dim3(256, 2), 256, 0, stream>>>(Wk, Wv, wkx, wvx, KVD * DMODEL / 4);

    gemm_bt<0><<<dim3(32, 8), 256, 0, stream>>>(qx, wqx, bq, Qp, BS, DMODEL, DMODEL);
    gemm_bt<0><<<dim3(32, 2), 256, 0, stream>>>(kx, wkx, bk, Kp, BS, KVD, DMODEL);
    gemm_bt<0><<<dim3(32, 2), 256, 0, stream>>>(vx, wvx, bv, Vp, BS, KVD, DMODEL);

    vtrans<<<dim3(32, 8), 256, 0, stream>>>(Vp, VT);

    float* attn_out = (float*)d_out + (size_t)BS * DMODEL;
    attn_ctx<<<512, 512, 0, stream>>>(Qp, Kp, VT, rinvArr, ctxb);
    attn_probs<<<4096, 256, 0, stream>>>(Qp, Kp, rinvArr, attn_out);

    gemm_bt<1><<<dim3(32, 8), 256, 0, stream>>>(ctxb, wox, bo, (float*)d_out, BS, DMODEL, DMODEL);
}

// Round 10
// 290.940 us; speedup vs baseline: 1.9034x; 1.0581x over previous
//
#include <hip/hip_runtime.h>

#define S_LEN 2048
#define DMODEL 1024
#define NH 16
#define NKVH 4
#define DKH 64
#define KVD 256
#define SCALE_LOG2E 0.18033688f  // (1/sqrt(64)) * log2(e)

typedef __bf16 bf16;
typedef bf16  bf16x8 __attribute__((ext_vector_type(8)));
typedef bf16  bf16x4 __attribute__((ext_vector_type(4)));
typedef float f32x4  __attribute__((ext_vector_type(4)));
typedef bf16x8 bf16x8_a __attribute__((may_alias));
typedef bf16x4 bf16x4_a __attribute__((may_alias));
typedef float f32x4g __attribute__((ext_vector_type(4), may_alias));

#define VWAIT(N)                                             \
    do {                                                     \
        asm volatile("s_waitcnt vmcnt(" #N ")" ::: "memory");\
        __builtin_amdgcn_sched_barrier(0);                   \
    } while (0)

// drain LDS ops then barrier: required when LDS WRITES must become visible cross-wave
#define LGKM0_BARRIER()                                       \
    do {                                                      \
        asm volatile("s_waitcnt lgkmcnt(0)" ::: "memory");    \
        __builtin_amdgcn_sched_barrier(0);                    \
        __builtin_amdgcn_s_barrier();                         \
        __builtin_amdgcn_sched_barrier(0);                    \
    } while (0)

__device__ __forceinline__ void gll16(const bf16* g, bf16* l) {
    __builtin_amdgcn_global_load_lds(
        (const __attribute__((address_space(1))) void*)g,
        (__attribute__((address_space(3))) void*)l, 16, 0, 0);
}

// ---------------- fused fp32 -> bf16 casts ----------------
__global__ __launch_bounds__(256) void cast3_bf16(const float* __restrict__ a,
                                                  const float* __restrict__ b,
                                                  const float* __restrict__ c,
                                                  bf16* __restrict__ oa, bf16* __restrict__ ob,
                                                  bf16* __restrict__ oc, int n4) {
    const float* src = blockIdx.y == 0 ? a : blockIdx.y == 1 ? b : c;
    bf16* dst = blockIdx.y == 0 ? oa : blockIdx.y == 1 ? ob : oc;
    int stride = gridDim.x * blockDim.x;
    for (int i = blockIdx.x * blockDim.x + threadIdx.x; i < n4; i += stride) {
        f32x4g v = ((const f32x4g*)src)[i];
        bf16x4 o;
        o[0] = (bf16)v[0]; o[1] = (bf16)v[1]; o[2] = (bf16)v[2]; o[3] = (bf16)v[3];
        ((bf16x4*)dst)[i] = o;
    }
}

__global__ __launch_bounds__(256) void cast2_bf16(const float* __restrict__ a,
                                                  const float* __restrict__ b,
                                                  bf16* __restrict__ oa, bf16* __restrict__ ob,
                                                  int n4) {
    const float* src = blockIdx.y == 0 ? a : b;
    bf16* dst = blockIdx.y == 0 ? oa : ob;
    int stride = gridDim.x * blockDim.x;
    for (int i = blockIdx.x * blockDim.x + threadIdx.x; i < n4; i += stride) {
        f32x4g v = ((const f32x4g*)src)[i];
        bf16x4 o;
        o[0] = (bf16)v[0]; o[1] = (bf16)v[1]; o[2] = (bf16)v[2]; o[3] = (bf16)v[3];
        ((bf16x4*)dst)[i] = o;
    }
}

// ---------------- NT GEMM: C[m][n] = sum_k A[m][k]*Bw[n][k] + bias[n] ----------------
template <int OUTF32>
__global__ __launch_bounds__(256) void gemm_bt(const bf16* __restrict__ A,
                                               const bf16* __restrict__ Bw,
                                               const float* __restrict__ bias,
                                               void* __restrict__ Cout,
                                               int M, int N, int K) {
    __shared__ bf16 As[4096];  // 128 x 32
    __shared__ bf16 Bs[4096];
    const int bm = blockIdx.x, bn = blockIdx.y;
    const int tid = threadIdx.x, wave = tid >> 6, lane = tid & 63;
    const int l15 = lane & 15, lhi = lane >> 4;
    const int wr = (wave >> 1) * 64, wc = (wave & 1) * 64;
    f32x4 acc[4][4] = {};
    const size_t arow0 = (size_t)bm * 128 * K;
    const size_t brow0 = (size_t)bn * 128 * K;

    for (int kt = 0; kt < K; kt += 32) {
#pragma unroll
        for (int i = 0; i < 2; ++i) {
            int base = i * 2048 + wave * 512;
            int flat = base + lane * 8;
            int r = flat >> 5, c = flat & 31;
            gll16(A + arow0 + (size_t)r * K + kt + c, &As[base]);
            gll16(Bw + brow0 + (size_t)r * K + kt + c, &Bs[base]);
        }
        __syncthreads();
        bf16x8 af[4], bfr[4];
#pragma unroll
        for (int mi = 0; mi < 4; ++mi)
            af[mi] = *(const bf16x8_a*)&As[(wr + mi * 16 + l15) * 32 + lhi * 8];
#pragma unroll
        for (int ni = 0; ni < 4; ++ni)
            bfr[ni] = *(const bf16x8_a*)&Bs[(wc + ni * 16 + l15) * 32 + lhi * 8];
#pragma unroll
        for (int mi = 0; mi < 4; ++mi)
#pragma unroll
            for (int ni = 0; ni < 4; ++ni)
                acc[mi][ni] = __builtin_amdgcn_mfma_f32_16x16x32_bf16(
                    af[mi], bfr[ni], acc[mi][ni], 0, 0, 0);
        __syncthreads();
    }
#pragma unroll
    for (int mi = 0; mi < 4; ++mi)
#pragma unroll
        for (int ni = 0; ni < 4; ++ni)
#pragma unroll
            for (int j = 0; j < 4; ++j) {
                int row = bm * 128 + wr + mi * 16 + lhi * 4 + j;
                int col = bn * 128 + wc + ni * 16 + l15;
                float v = acc[mi][ni][j] + bias[col];
                if (OUTF32)
                    ((float*)Cout)[(size_t)row * N + col] = v;
                else
                    ((bf16*)Cout)[(size_t)row * N + col] = (bf16)v;
            }
}

// ---------------- V transpose: Vp[b*2048+s][g*64+d] -> VT[b][g][d][s] ----------------
__global__ __launch_bounds__(256) void vtrans(const bf16* __restrict__ V,
                                              bf16* __restrict__ VT) {
    __shared__ bf16 t[64][65];
    const int s0 = blockIdx.x * 64;
    const int bg = blockIdx.y;
    const int b = bg >> 2, g = bg & 3;
#pragma unroll
    for (int i = 0; i < 16; ++i) {
        int flat = threadIdx.x + i * 256;
        int r = flat >> 6, c = flat & 63;
        t[c][r] = V[(size_t)(b * S_LEN + s0 + r) * KVD + g * DKH + c];
    }
    __syncthreads();
#pragma unroll
    for (int i = 0; i < 16; ++i) {
        int flat = threadIdx.x + i * 256;
        int d = flat >> 6, si = flat & 63;
        VT[((size_t)bg * DKH + d) * S_LEN + s0 + si] = t[d][si];
    }
}

// ---------------- merged attention: denom + probs + PV in one kernel ----------------
// grid 2048 (XCD-swizzled) = bh(32) x qt(64: 32 q-rows); block 512 = 8 waves (2 wq x 4 wk).
// Pass A: lsum over 32 chunks of 64 keys (K ring-4). Pass B: QK -> p=exp*rinv ->
// {coalesced f32 prob stores via Pf} + {PV on NORMALIZED P via Pb} per chunk (K,V ring-2).
__global__ __launch_bounds__(512, 4) void attn_all(const bf16* __restrict__ Qp,
                                                   const bf16* __restrict__ Kp,
                                                   const bf16* __restrict__ VT,
                                                   float* __restrict__ attn_out,
                                                   bf16* __restrict__ ctx) {
    __shared__ bf16 KV[4][4096];  // 32 KB: pass A = K ring4; pass B = K{0,1}, V{2,3}
    __shared__ float Pf[2048];    // 8 KB  [32 q][64 k] f32, 4-bit slot XOR swizzle
    __shared__ bf16 Pb[2048];     // 4 KB  [32 q][64 k] bf16, 3-bit swizzle
    const int raw = blockIdx.x;
    const int wg = (raw & 7) * 256 + (raw >> 3);  // 2048 % 8 == 0: bijective
    const int bh = wg >> 6;
    const int qt = wg & 63;
    const int h = bh & (NH - 1), b = bh >> 4, g = h >> 2;
    const int tid = threadIdx.x, wave = tid >> 6, lane = tid & 63;
    const int l15 = lane & 15, lhi = lane >> 4;
    const int wq = wave >> 2, wk = wave & 3;  // wk doubles as dv-tile in PV
    const int qrow0 = qt * 32;
    const int sw = (l15 & 7) << 4;

    // Q fragments for this wave's 16 q-rows
    const bf16* qb =
        Qp + (size_t)(b * S_LEN + qrow0 + wq * 16 + l15) * DMODEL + h * DKH + lhi * 8;
    bf16x8 aq0 = *(const bf16x8_a*)qb;
    bf16x8 aq1 = *(const bf16x8_a*)(qb + 32);

    // staging: thread -> (row tid>>3, 16B slot tid&7), source slot pre-swizzled
    const int srow = tid >> 3;                 // 0..63 (key row for K, dv row for V)
    const int scc = (tid & 7) ^ (srow & 7);
    const bf16* ksrc = Kp + (size_t)(b * S_LEN + srow) * KVD + g * DKH + scc * 8;
    const bf16* vsrc = VT + ((size_t)(b * NKVH + g) * DKH + srow) * S_LEN + scc * 8;

    // ================= pass A: denominators (K ring-4) =================
    gll16(ksrc, &KV[0][wave * 512]);
    gll16(ksrc + (size_t)64 * KVD, &KV[1][wave * 512]);
    float lsum = 0.f;
    for (int c = 0; c < 32; ++c) {
        if (c < 30) gll16(ksrc + (size_t)((c + 2) * 64) * KVD, &KV[(c + 2) & 3][wave * 512]);
        if (c < 30) { VWAIT(2); } else if (c == 30) { VWAIT(1); } else { VWAIT(0); }
        __builtin_amdgcn_s_barrier();
        const char* kc = (const char*)&KV[c & 3][0];
        const int rb = (wk * 16 + l15) * 128;
        bf16x8 k0 = *(const bf16x8_a*)(kc + rb + ((lhi * 16) ^ sw));
        bf16x8 k1 = *(const bf16x8_a*)(kc + rb + ((lhi * 16 + 64) ^ sw));
        f32x4 a = {0.f, 0.f, 0.f, 0.f};
        __builtin_amdgcn_s_setprio(1);
        a = __builtin_amdgcn_mfma_f32_16x16x32_bf16(k0, aq0, a, 0, 0, 0);
        a = __builtin_amdgcn_mfma_f32_16x16x32_bf16(k1, aq1, a, 0, 0, 0);
        __builtin_amdgcn_s_setprio(0);
        lsum += __builtin_exp2f(a[0] * SCALE_LOG2E) + __builtin_exp2f(a[1] * SCALE_LOG2E) +
                __builtin_exp2f(a[2] * SCALE_LOG2E) + __builtin_exp2f(a[3] * SCALE_LOG2E);
    }
    // reduce: lanes {l15, +16, +32, +48} share q = wq*16+l15
    lsum += __shfl_xor(lsum, 16, 64);
    lsum += __shfl_xor(lsum, 32, 64);
    float* red = (float*)&Pf[0];  // [8 waves][16 q]
    LGKM0_BARRIER();              // all waves finished pass A (KV safe to restage)
    if (lane < 16) red[wave * 16 + lane] = lsum;
    gll16(ksrc, &KV[0][wave * 512]);  // pass B prologue: K(0), V(0)
    gll16(vsrc, &KV[2][wave * 512]);
    LGKM0_BARRIER();  // red visible
    float lt = red[(wq * 4 + 0) * 16 + l15] + red[(wq * 4 + 1) * 16 + l15] +
               red[(wq * 4 + 2) * 16 + l15] + red[(wq * 4 + 3) * 16 + l15];
    const float rinv = 1.0f / lt;
    LGKM0_BARRIER();  // red reads complete before Pf reuse

    // ================= pass B: probs + PV (K,V ring-2) =================
    f32x4 cacc = {0.f, 0.f, 0.f, 0.f};
    float* arow = attn_out + ((size_t)bh * S_LEN + qrow0) * S_LEN;
    char* pfb = (char*)&Pf[0];
    char* pbb = (char*)&Pb[0];
    const int ql = wq * 16 + l15;              // q-local row this lane produces
    const int pfw = ql * 256 + (((wk * 4 + lhi) ^ (ql & 15)) << 4);  // Pf write byte
    const int pbw = (ql * 128 + wk * 32 + lhi * 8) ^ sw;             // Pb write byte
    const int strow = tid >> 4;                // 0..31 store row
    const int stslot = tid & 15;
    const int pfr = strow * 256 + ((stslot ^ (strow & 15)) << 4);    // Pf read byte
    float* gst = arow + (size_t)strow * S_LEN + stslot * 4;

    for (int c = 0; c < 32; ++c) {
        if (c == 0) { VWAIT(0); } else { VWAIT(1); }
        __builtin_amdgcn_s_barrier();  // K(c), V(c) resident
        // QK(c): out [key = wk*16+lhi*4+j][q = wq*16+l15]
        const char* kc = (const char*)&KV[c & 1][0];
        const int rb = (wk * 16 + l15) * 128;
        bf16x8 k0 = *(const bf16x8_a*)(kc + rb + ((lhi * 16) ^ sw));
        bf16x8 k1 = *(const bf16x8_a*)(kc + rb + ((lhi * 16 + 64) ^ sw));
        f32x4 a = {0.f, 0.f, 0.f, 0.f};
        __builtin_amdgcn_s_setprio(1);
        a = __builtin_amdgcn_mfma_f32_16x16x32_bf16(k0, aq0, a, 0, 0, 0);
        a = __builtin_amdgcn_mfma_f32_16x16x32_bf16(k1, aq1, a, 0, 0, 0);
        __builtin_amdgcn_s_setprio(0);
        f32x4 p4;
        bf16x4 pb4;
#pragma unroll
        for (int j = 0; j < 4; ++j) {
            p4[j] = __builtin_exp2f(a[j] * SCALE_LOG2E) * rinv;
            pb4[j] = (bf16)p4[j];
        }
        *(f32x4g*)(pfb + pfw) = p4;
        *(bf16x4_a*)(pbb + pbw) = pb4;
        LGKM0_BARRIER();  // P visible to all waves
        // restage: buffers (c+1)&1 were last read pre-previous-barrier -> race-free
        if (c < 31) {
            gll16(ksrc + (size_t)((c + 1) * 64) * KVD, &KV[(c + 1) & 1][wave * 512]);
            gll16(vsrc + (c + 1) * 64, &KV[2 + ((c + 1) & 1)][wave * 512]);
            __builtin_amdgcn_sched_barrier(0);  // pin: prob store must stay AFTER gll16s
        }
        // PV(c): wave = (wq, dv-tile wk); A = normalized P from Pb, B = V^T
        bf16x8 ap0 = *(const bf16x8_a*)(pbb + ((ql * 128 + lhi * 16) ^ sw));
        bf16x8 ap1 = *(const bf16x8_a*)(pbb + ((ql * 128 + 64 + lhi * 16) ^ sw));
        const char* vc = (const char*)&KV[2 + (c & 1)][0];
        const int vb = (wk * 16 + l15) * 128;
        bf16x8 v0 = *(const bf16x8_a*)(vc + vb + ((lhi * 16) ^ sw));
        bf16x8 v1 = *(const bf16x8_a*)(vc + vb + ((lhi * 16 + 64) ^ sw));
        __builtin_amdgcn_s_setprio(1);
        cacc = __builtin_amdgcn_mfma_f32_16x16x32_bf16(ap0, v0, cacc, 0, 0, 0);
        cacc = __builtin_amdgcn_mfma_f32_16x16x32_bf16(ap1, v1, cacc, 0, 0, 0);
        __builtin_amdgcn_s_setprio(0);
        // coalesced prob store: 256B contiguous per 16-lane group
        f32x4 pv = *(const f32x4g*)(pfb + pfr);
        *(f32x4g*)(gst + c * 64) = pv;
    }
    // ctx write: q = qrow0 + wq*16 + lhi*4 + j, dv = h*64 + wk*16 + l15
    // P already normalized -> NO second rinv multiply (R9 bug)
#pragma unroll
    for (int j = 0; j < 4; ++j) {
        int row = qrow0 + wq * 16 + lhi * 4 + j;
        ctx[(size_t)(b * S_LEN + row) * DMODEL + h * DKH + wk * 16 + l15] = (bf16)cacc[j];
    }
}

extern "C" void kernel_launch(void* const* d_in, const int* in_sizes, int n_in,
                              void* d_out, int out_size, void* d_ws, size_t ws_size,
                              hipStream_t stream) {
    const float* query = (const float*)d_in[0];
    const float* key_i = (const float*)d_in[1];
    const float* value = (const float*)d_in[2];
    const float* Wq = (const float*)d_in[3];
    const float* bq = (const float*)d_in[4];
    const float* Wk = (const float*)d_in[5];
    const float* bk = (const float*)d_in[6];
    const float* Wv = (const float*)d_in[7];
    const float* bv = (const float*)d_in[8];
    const float* Wo = (const float*)d_in[9];
    const float* bo = (const float*)d_in[10];

    char* ws = (char*)d_ws;
    bf16* qx = (bf16*)(ws + 0);
    bf16* kx = (bf16*)(ws + ((size_t)8 << 20));
    bf16* vx = (bf16*)(ws + ((size_t)16 << 20));
    bf16* wqx = (bf16*)(ws + ((size_t)32 << 20));
    bf16* wkx = (bf16*)(ws + ((size_t)34 << 20));
    bf16* wvx = (bf16*)(ws + ((size_t)34 << 20) + ((size_t)512 << 10));
    bf16* wox = (bf16*)(ws + ((size_t)35 << 20));
    bf16* Qp = (bf16*)(ws + ((size_t)37 << 20));
    bf16* Kp = (bf16*)(ws + ((size_t)45 << 20));
    bf16* Vp = (bf16*)(ws + ((size_t)47 << 20));
    bf16* VT = (bf16*)(ws + ((size_t)49 << 20));
    bf16* ctxb = (bf16*)(ws + ((size_t)51 << 20));

    const int BS = 2 * S_LEN;  // 4096 rows

    cast3_bf16<<<dim3(1024, 3), 256, 0, stream>>>(query, key_i, value, qx, kx, vx,
                                                  BS * DMODEL / 4);
    cast2_bf16<<<dim3(1024, 2), 256, 0, stream>>>(Wq, Wo, wqx, wox, DMODEL * DMODEL / 4);
    cast2_bf16<<<dim3(256, 2), 256, 0, stream>>>(Wk, Wv, wkx, wvx, KVD * DMODEL / 4);

    gemm_bt<0><<<dim3(32, 8), 256, 0, stream>>>(qx, wqx, bq, Qp, BS, DMODEL, DMODEL);
    gemm_bt<0><<<dim3(32, 2), 256, 0, stream>>>(kx, wkx, bk, Kp, BS, KVD, DMODEL);
    gemm_bt<0><<<dim3(32, 2), 256, 0, stream>>>(vx, wvx, bv, Vp, BS, KVD, DMODEL);

    vtrans<<<dim3(32, 8), 256, 0, stream>>>(Vp, VT);

    float* attn_out = (float*)d_out + (size_t)BS * DMODEL;
    attn_all<<<2048, 512, 0, stream>>>(Qp, Kp, VT, attn_out, ctxb);

    gemm_bt<1><<<dim3(32, 8), 256, 0, stream>>>(ctxb, wox, bo, (float*)d_out, BS, DMODEL, DMODEL);
}